// Round 1
// baseline (10747.491 us; speedup 1.0000x reference)
//
#include <hip/hip_runtime.h>
#include <hip/hip_bf16.h>

#define N_NODES 98304
#define N_GRAPHS 2048
#define NPG 48
#define N_EDGES 393216
#define NODE_IN 128
#define EMB 64
#define HID 256
#define N_LAYERS_ 6
#define ATTN_DIM_ 256
#define OUT_DIM_ 1024

// ---------------- counts: h[n] += cnt[n] * MLP(h[n]) ----------------
__global__ __launch_bounds__(256) void zero_cnt_kernel(int* __restrict__ cnt) {
    int i = blockIdx.x * 256 + threadIdx.x;
    if (i < N_NODES) cnt[i] = 0;
}

__global__ __launch_bounds__(256) void hist_kernel(const int* __restrict__ row,
                                                   int* __restrict__ cnt) {
    int i = blockIdx.x * 256 + threadIdx.x;
    if (i < N_EDGES) atomicAdd(&cnt[row[i]], 1);
}

// ---------------- embed: h = x @ W_embed + b_embed  [98304,128]@[128,64] ----
// grid 6144 (16 nodes/block), block 256
__global__ __launch_bounds__(256) void embed_kernel(
    const float* __restrict__ x, const float* __restrict__ W,
    const float* __restrict__ b, float* __restrict__ h)
{
    __shared__ float xs[16 * 128];
    const int tid = threadIdx.x;
    const int base = blockIdx.x * 16;
    const float4* src = reinterpret_cast<const float4*>(x + (size_t)base * 128);
    float4* dst = reinterpret_cast<float4*>(xs);
    dst[tid] = src[tid];
    dst[tid + 256] = src[tid + 256];
    __syncthreads();
    const int n = tid >> 4;    // 0..15
    const int cg = tid & 15;   // cols cg*4..cg*4+3
    float acc[4];
    #pragma unroll
    for (int c = 0; c < 4; c++) acc[c] = b[cg * 4 + c];
    for (int k = 0; k < 128; k++) {
        float a = xs[n * 128 + k];
        float4 w = *reinterpret_cast<const float4*>(W + k * 64 + cg * 4);
        acc[0] += a * w.x; acc[1] += a * w.y; acc[2] += a * w.z; acc[3] += a * w.w;
    }
    *reinterpret_cast<float4*>(h + (size_t)(base + n) * 64 + cg * 4) =
        make_float4(acc[0], acc[1], acc[2], acc[3]);
}

// ---------------- fused MLP layer: h += cnt * (relu(relu(h@W1+b1)@W2+b2)@W3+b3)
// 16 nodes/block, 256 threads, LDS 52KB -> ~3 blocks/CU
__global__ __launch_bounds__(256) void layer_kernel(
    float* __restrict__ h, const int* __restrict__ cnt,
    const float* __restrict__ W1, const float* __restrict__ b1,
    const float* __restrict__ W2, const float* __restrict__ b2,
    const float* __restrict__ W3, const float* __restrict__ b3)
{
    __shared__ float hs[16 * 64];    // 4KB
    __shared__ float m1s[16 * 256];  // 16KB
    __shared__ float m2s[16 * 512];  // 32KB
    const int tid = threadIdx.x;
    const int base = blockIdx.x * 16;
    {   // load h tile: 1024 floats = 256 float4
        const float4* src = reinterpret_cast<const float4*>(h + (size_t)base * 64);
        reinterpret_cast<float4*>(hs)[tid] = src[tid];
    }
    __syncthreads();
    // Stage A: m1 = relu(hs @ W1 + b1)   [16 x 256], K=64
    {
        const int ng = tid >> 5;   // node pair ng*2
        const int cg = tid & 31;   // cols cg*8
        float acc[2][8];
        #pragma unroll
        for (int i = 0; i < 2; i++)
            #pragma unroll
            for (int c = 0; c < 8; c++) acc[i][c] = b1[cg * 8 + c];
        for (int k = 0; k < 64; k++) {
            float4 w0 = *reinterpret_cast<const float4*>(W1 + k * 256 + cg * 8);
            float4 w1 = *reinterpret_cast<const float4*>(W1 + k * 256 + cg * 8 + 4);
            #pragma unroll
            for (int i = 0; i < 2; i++) {
                float a = hs[(ng * 2 + i) * 64 + k];
                acc[i][0] += a * w0.x; acc[i][1] += a * w0.y;
                acc[i][2] += a * w0.z; acc[i][3] += a * w0.w;
                acc[i][4] += a * w1.x; acc[i][5] += a * w1.y;
                acc[i][6] += a * w1.z; acc[i][7] += a * w1.w;
            }
        }
        #pragma unroll
        for (int i = 0; i < 2; i++)
            #pragma unroll
            for (int c = 0; c < 8; c++)
                m1s[(ng * 2 + i) * 256 + cg * 8 + c] = fmaxf(acc[i][c], 0.f);
    }
    __syncthreads();
    // Stage B: m2 = relu(m1 @ W2 + b2)   [16 x 512], K=256
    {
        const int ng = tid >> 5;   // node pair ng*2
        const int cg = tid & 31;   // cols cg*16
        float acc[2][16];
        #pragma unroll
        for (int i = 0; i < 2; i++)
            #pragma unroll
            for (int c = 0; c < 16; c++) acc[i][c] = b2[cg * 16 + c];
        for (int k = 0; k < 256; k++) {
            const float* W2k = W2 + (size_t)k * 512 + cg * 16;
            float4 w0 = *reinterpret_cast<const float4*>(W2k);
            float4 w1 = *reinterpret_cast<const float4*>(W2k + 4);
            float4 w2 = *reinterpret_cast<const float4*>(W2k + 8);
            float4 w3 = *reinterpret_cast<const float4*>(W2k + 12);
            #pragma unroll
            for (int i = 0; i < 2; i++) {
                float a = m1s[(ng * 2 + i) * 256 + k];
                acc[i][0]  += a * w0.x; acc[i][1]  += a * w0.y;
                acc[i][2]  += a * w0.z; acc[i][3]  += a * w0.w;
                acc[i][4]  += a * w1.x; acc[i][5]  += a * w1.y;
                acc[i][6]  += a * w1.z; acc[i][7]  += a * w1.w;
                acc[i][8]  += a * w2.x; acc[i][9]  += a * w2.y;
                acc[i][10] += a * w2.z; acc[i][11] += a * w2.w;
                acc[i][12] += a * w3.x; acc[i][13] += a * w3.y;
                acc[i][14] += a * w3.z; acc[i][15] += a * w3.w;
            }
        }
        #pragma unroll
        for (int i = 0; i < 2; i++)
            #pragma unroll
            for (int c = 0; c < 16; c++)
                m2s[(ng * 2 + i) * 512 + cg * 16 + c] = fmaxf(acc[i][c], 0.f);
    }
    __syncthreads();
    // Stage C: dh = m2 @ W3 + b3; h += cnt * dh   [16 x 64], K=512
    {
        const int n = tid >> 4;   // 1 node
        const int cg = tid & 15;  // cols cg*4
        float acc[4];
        #pragma unroll
        for (int c = 0; c < 4; c++) acc[c] = b3[cg * 4 + c];
        for (int k = 0; k < 512; k++) {
            float a = m2s[n * 512 + k];
            float4 w = *reinterpret_cast<const float4*>(W3 + k * 64 + cg * 4);
            acc[0] += a * w.x; acc[1] += a * w.y; acc[2] += a * w.z; acc[3] += a * w.w;
        }
        float c = (float)cnt[base + n];
        float4 old = *reinterpret_cast<const float4*>(hs + n * 64 + cg * 4);
        *reinterpret_cast<float4*>(h + (size_t)(base + n) * 64 + cg * 4) =
            make_float4(old.x + c * acc[0], old.y + c * acc[1],
                        old.z + c * acc[2], old.w + c * acc[3]);
    }
}

// ---------------- precompute score vectors: s[hd] = Wp @ (Wk[:,hd] @ qh_hd) ----
// prec layout: [0..255] = s[hd][i] (hd*64+i), [256..259] = d[hd]
__global__ __launch_bounds__(256) void prec_kernel(
    const float* __restrict__ q, const float* __restrict__ W_in,
    const float* __restrict__ b_in, const float* __restrict__ Wp,
    const float* __restrict__ bp, float* __restrict__ prec)
{
    __shared__ float qh_s[256];
    __shared__ float u_s[4 * 256];
    const int tid = threadIdx.x;
    {   // qh = (q @ Wq + bq) / 8
        float acc = b_in[tid];
        for (int j = 0; j < 256; j++) acc += q[j] * W_in[j * 768 + tid];
        qh_s[tid] = acc * 0.125f;
    }
    __syncthreads();
    {   // u[hd][j] = sum_d Wk[j][hd*64+d] * qh[hd][d]
        #pragma unroll
        for (int hd = 0; hd < 4; hd++) {
            float a = 0.f;
            for (int d = 0; d < 64; d++)
                a += W_in[tid * 768 + 256 + hd * 64 + d] * qh_s[hd * 64 + d];
            u_s[hd * 256 + tid] = a;
        }
    }
    __syncthreads();
    {   // s[hd][i] = sum_j Wp[i][j] * u[hd][j]
        int hd = tid >> 6, i = tid & 63;
        float a = 0.f;
        for (int j = 0; j < 256; j++) a += Wp[i * 256 + j] * u_s[hd * 256 + j];
        prec[hd * 64 + i] = a;
    }
    if (tid < 4) {  // d[hd] = bp . u[hd] + bk[hd] . qh[hd]
        float a = 0.f;
        for (int j = 0; j < 256; j++) a += bp[j] * u_s[tid * 256 + j];
        for (int d = 0; d < 64; d++) a += b_in[256 + tid * 64 + d] * qh_s[tid * 64 + d];
        prec[256 + tid] = a;
    }
}

// ---------------- attention pooling: hw[g][hd] = sum_n softmax_w * h[n] --------
// one wave per graph (48 contiguous nodes)
__global__ __launch_bounds__(64) void attnpool_kernel(
    const float* __restrict__ h, const float* __restrict__ prec,
    float* __restrict__ hw)
{
    __shared__ float hs[48 * 65];
    __shared__ float ss[4 * 64];
    __shared__ float ds_[4];
    __shared__ float wl[48 * 4];
    const int lane = threadIdx.x;
    const int g = blockIdx.x;
    #pragma unroll
    for (int hd = 0; hd < 4; hd++) ss[hd * 64 + lane] = prec[hd * 64 + lane];
    if (lane < 4) ds_[lane] = prec[256 + lane];
    for (int r = 0; r < 48; r++)
        hs[r * 65 + lane] = h[((size_t)g * 48 + r) * 64 + lane];
    __syncthreads();
    float sc[4] = {0.f, 0.f, 0.f, 0.f};
    if (lane < 48) {
        #pragma unroll
        for (int hd = 0; hd < 4; hd++) sc[hd] = ds_[hd];
        for (int c = 0; c < 64; c++) {
            float a = hs[lane * 65 + c];
            #pragma unroll
            for (int hd = 0; hd < 4; hd++) sc[hd] += a * ss[hd * 64 + c];
        }
    }
    #pragma unroll
    for (int hd = 0; hd < 4; hd++) {
        float v = (lane < 48) ? sc[hd] : -3.0e38f;
        #pragma unroll
        for (int m = 32; m >= 1; m >>= 1) v = fmaxf(v, __shfl_xor(v, m, 64));
        float e = (lane < 48) ? __expf(sc[hd] - v) : 0.f;
        float s = e;
        #pragma unroll
        for (int m = 32; m >= 1; m >>= 1) s += __shfl_xor(s, m, 64);
        if (lane < 48) wl[lane * 4 + hd] = e / s;
    }
    __syncthreads();
    float acc[4] = {0.f, 0.f, 0.f, 0.f};
    for (int n = 0; n < 48; n++) {
        float hv = hs[n * 65 + lane];
        #pragma unroll
        for (int hd = 0; hd < 4; hd++) acc[hd] += wl[n * 4 + hd] * hv;
    }
    #pragma unroll
    for (int hd = 0; hd < 4; hd++) hw[(size_t)g * 256 + hd * 64 + lane] = acc[hd];
}

// ---------------- tail: pooled -> attn -> t -> LN -> out   (8 graphs/block) ----
__global__ __launch_bounds__(256) void tail_kernel(
    const float* __restrict__ hw,
    const float* __restrict__ Wp, const float* __restrict__ bp,
    const float* __restrict__ W_in, const float* __restrict__ b_in,
    const float* __restrict__ W_out, const float* __restrict__ b_out,
    const float* __restrict__ Wh1, const float* __restrict__ bh1,
    const float* __restrict__ ln_g, const float* __restrict__ ln_b,
    const float* __restrict__ Wh2, const float* __restrict__ bh2,
    float* __restrict__ out)
{
    __shared__ float hw_s[8 * 256];
    __shared__ float hpw_s[8 * 1024];   // [g][hd][j]
    __shared__ float pooled_s[8 * 256];
    __shared__ float attn_s[8 * 256];   // relu applied
    __shared__ float t_s[8 * 256];
    __shared__ float mu_s[8], rs_s[8];
    const int tid = threadIdx.x;
    const int g0 = blockIdx.x * 8;
    #pragma unroll
    for (int r = 0; r < 8; r++)
        hw_s[r * 256 + tid] = hw[(size_t)g0 * 256 + r * 256 + tid];
    __syncthreads();
    // Stage 1: hpw[g][hd][:] = hw[g][hd] @ Wp + bp    (j = tid)
    {
        float acc[8][4];
        #pragma unroll
        for (int g = 0; g < 8; g++)
            #pragma unroll
            for (int hd = 0; hd < 4; hd++) acc[g][hd] = 0.f;
        for (int i = 0; i < 64; i++) {
            float w = Wp[i * 256 + tid];
            #pragma unroll
            for (int g = 0; g < 8; g++)
                #pragma unroll
                for (int hd = 0; hd < 4; hd++)
                    acc[g][hd] += hw_s[g * 256 + hd * 64 + i] * w;
        }
        float bpj = bp[tid];
        #pragma unroll
        for (int g = 0; g < 8; g++)
            #pragma unroll
            for (int hd = 0; hd < 4; hd++)
                hpw_s[g * 1024 + hd * 256 + tid] = acc[g][hd] + bpj;
    }
    __syncthreads();
    // Stage 2: pooled[g][p] = hpw[g][hd] . Wv[:,p] + bv[p]   (p = tid, hd = p>>6)
    {
        const int hd = tid >> 6;
        float acc[8];
        #pragma unroll
        for (int g = 0; g < 8; g++) acc[g] = 0.f;
        for (int j = 0; j < 256; j++) {
            float w = W_in[j * 768 + 512 + tid];
            #pragma unroll
            for (int g = 0; g < 8; g++)
                acc[g] += hpw_s[g * 1024 + hd * 256 + j] * w;
        }
        float bb = b_in[512 + tid];
        #pragma unroll
        for (int g = 0; g < 8; g++) pooled_s[g * 256 + tid] = acc[g] + bb;
    }
    __syncthreads();
    // Stage 3: attn_relu[g][c] = relu(pooled[g] @ W_out + b_out)
    {
        float acc[8];
        #pragma unroll
        for (int g = 0; g < 8; g++) acc[g] = 0.f;
        for (int j = 0; j < 256; j++) {
            float w = W_out[j * 256 + tid];
            #pragma unroll
            for (int g = 0; g < 8; g++) acc[g] += pooled_s[g * 256 + j] * w;
        }
        float bb = b_out[tid];
        #pragma unroll
        for (int g = 0; g < 8; g++)
            attn_s[g * 256 + tid] = fmaxf(acc[g] + bb, 0.f);
    }
    __syncthreads();
    // Stage 4: t[g][c] = relu(attn_relu[g] @ Wh1 + bh1)
    {
        float acc[8];
        #pragma unroll
        for (int g = 0; g < 8; g++) acc[g] = 0.f;
        for (int j = 0; j < 256; j++) {
            float w = Wh1[j * 256 + tid];
            #pragma unroll
            for (int g = 0; g < 8; g++) acc[g] += attn_s[g * 256 + j] * w;
        }
        float bb = bh1[tid];
        #pragma unroll
        for (int g = 0; g < 8; g++)
            t_s[g * 256 + tid] = fmaxf(acc[g] + bb, 0.f);
    }
    __syncthreads();
    // Stage 5: layernorm stats per graph
    if (tid < 8) {
        float s = 0.f;
        for (int c = 0; c < 256; c++) s += t_s[tid * 256 + c];
        float mu = s * (1.f / 256.f);
        float v = 0.f;
        for (int c = 0; c < 256; c++) {
            float d = t_s[tid * 256 + c] - mu;
            v += d * d;
        }
        v *= (1.f / 256.f);
        mu_s[tid] = mu;
        rs_s[tid] = rsqrtf(v + 1e-5f);
    }
    __syncthreads();
    {
        float gg = ln_g[tid], bb = ln_b[tid];
        #pragma unroll
        for (int r = 0; r < 8; r++)
            t_s[r * 256 + tid] = (t_s[r * 256 + tid] - mu_s[r]) * rs_s[r] * gg + bb;
    }
    __syncthreads();
    // Stage 6: out[g][:] = t[g] @ Wh2 + bh2   (thread -> 4 output cols)
    {
        float acc[8][4];
        float4 bb = *reinterpret_cast<const float4*>(bh2 + tid * 4);
        #pragma unroll
        for (int g = 0; g < 8; g++) {
            acc[g][0] = bb.x; acc[g][1] = bb.y; acc[g][2] = bb.z; acc[g][3] = bb.w;
        }
        for (int j = 0; j < 256; j++) {
            float4 w = *reinterpret_cast<const float4*>(Wh2 + (size_t)j * 1024 + tid * 4);
            #pragma unroll
            for (int g = 0; g < 8; g++) {
                float tv = t_s[g * 256 + j];
                acc[g][0] += tv * w.x; acc[g][1] += tv * w.y;
                acc[g][2] += tv * w.z; acc[g][3] += tv * w.w;
            }
        }
        #pragma unroll
        for (int g = 0; g < 8; g++)
            *reinterpret_cast<float4*>(out + (size_t)(g0 + g) * 1024 + tid * 4) =
                make_float4(acc[g][0], acc[g][1], acc[g][2], acc[g][3]);
    }
}

extern "C" void kernel_launch(void* const* d_in, const int* in_sizes, int n_in,
                              void* d_out, int out_size, void* d_ws, size_t ws_size,
                              hipStream_t stream) {
    const float* x       = (const float*)d_in[0];
    const int*   edge    = (const int*)d_in[1];
    // d_in[2] = batch (contiguous arange//48, structure used implicitly)
    const float* W_embed = (const float*)d_in[3];
    const float* b_embed = (const float*)d_in[4];
    const float* W1 = (const float*)d_in[5];
    const float* b1 = (const float*)d_in[6];
    const float* W2 = (const float*)d_in[7];
    const float* b2 = (const float*)d_in[8];
    const float* W3 = (const float*)d_in[9];
    const float* b3 = (const float*)d_in[10];
    const float* Wp = (const float*)d_in[11];
    const float* bp = (const float*)d_in[12];
    const float* q  = (const float*)d_in[13];
    const float* W_in  = (const float*)d_in[14];
    const float* b_in  = (const float*)d_in[15];
    const float* W_out = (const float*)d_in[16];
    const float* b_out = (const float*)d_in[17];
    const float* Wh1 = (const float*)d_in[18];
    const float* bh1 = (const float*)d_in[19];
    const float* ln_g = (const float*)d_in[20];
    const float* ln_b = (const float*)d_in[21];
    const float* Wh2 = (const float*)d_in[22];
    const float* bh2 = (const float*)d_in[23];
    float* out = (float*)d_out;

    char* ws = (char*)d_ws;
    int*   cnt  = (int*)ws;                                       // 98304 ints
    float* h    = (float*)(ws + (size_t)N_NODES * 4);             // 98304*64 f32
    float* hw   = (float*)(ws + (size_t)N_NODES * 4 + (size_t)N_NODES * 64 * 4);
    float* prec = (float*)(ws + (size_t)N_NODES * 4 + (size_t)N_NODES * 64 * 4
                              + (size_t)N_GRAPHS * 256 * 4);      // 260 f32

    zero_cnt_kernel<<<N_NODES / 256, 256, 0, stream>>>(cnt);
    hist_kernel<<<N_EDGES / 256, 256, 0, stream>>>(edge, cnt);
    embed_kernel<<<N_NODES / 16, 256, 0, stream>>>(x, W_embed, b_embed, h);
    for (int l = 0; l < N_LAYERS_; l++) {
        layer_kernel<<<N_NODES / 16, 256, 0, stream>>>(
            h, cnt,
            W1 + (size_t)l * EMB * HID,      b1 + (size_t)l * HID,
            W2 + (size_t)l * HID * 2 * HID,  b2 + (size_t)l * 2 * HID,
            W3 + (size_t)l * 2 * HID * EMB,  b3 + (size_t)l * EMB);
    }
    prec_kernel<<<1, 256, 0, stream>>>(q, W_in, b_in, Wp, bp, prec);
    attnpool_kernel<<<N_GRAPHS, 64, 0, stream>>>(h, prec, hw);
    tail_kernel<<<N_GRAPHS / 8, 256, 0, stream>>>(hw, Wp, bp, W_in, b_in,
                                                  W_out, b_out, Wh1, bh1,
                                                  ln_g, ln_b, Wh2, bh2, out);
}

// Round 3
// 1808.811 us; speedup vs baseline: 5.9417x; 5.9417x over previous
//
#include <hip/hip_runtime.h>
#include <hip/hip_bf16.h>

#define N_NODES 98304
#define N_GRAPHS 2048
#define N_EDGES 393216
#define EMB 64
#define HID 256
#define N_LAYERS_ 6

typedef __attribute__((ext_vector_type(8))) short short8v;
typedef __attribute__((ext_vector_type(4))) float f32x4;
#define MFMA16(a, b, c) __builtin_amdgcn_mfma_f32_16x16x32_bf16(a, b, c, 0, 0, 0)

__device__ __forceinline__ unsigned short f2bf(float x) {
    unsigned int u = __float_as_uint(x);
    u = (u + 0x7fffu + ((u >> 16) & 1u)) >> 16;
    return (unsigned short)u;
}
__device__ __forceinline__ float bf2f(unsigned short h) {
    return __uint_as_float(((unsigned int)h) << 16);
}
// swizzled index in ushort units: XOR bits 3..5 (16B-slot id) with row&7
__device__ __forceinline__ int swz(int row, int col, int rowc) {
    return (row * rowc + col) ^ ((row & 7) << 3);
}

// ---------------- histogram of edge rows ----------------
__global__ __launch_bounds__(256) void zero_cnt_kernel(int* __restrict__ cnt) {
    int i = blockIdx.x * 256 + threadIdx.x;
    if (i < N_NODES) cnt[i] = 0;
}
__global__ __launch_bounds__(256) void hist_kernel(const int* __restrict__ row,
                                                   int* __restrict__ cnt) {
    int i = blockIdx.x * 256 + threadIdx.x;
    if (i < N_EDGES) atomicAdd(&cnt[row[i]], 1);
}

// ---------------- weight prep: fp32 [L][K][N] -> hi/lo bf16 MFMA B-frags ----
// frag layout per layer: [(nf*KS + ks)*64 + lane]*8 ; lane holds
// B[k = ks*32 + (lane>>4)*8 + j][n = nf*16 + (lane&15)]
__global__ __launch_bounds__(64) void prep_frag_kernel(
    const float* __restrict__ W, unsigned short* __restrict__ oh,
    unsigned short* __restrict__ ol, int K, int N)
{
    const int NF = N >> 4, KS = K >> 5;
    const int fpl = NF * KS;
    const int layer = blockIdx.x / fpl;
    const int fid = blockIdx.x % fpl;
    const int nf = fid / KS, ks = fid % KS;
    const int lane = threadIdx.x;
    const float* Wl = W + (size_t)layer * K * N;
    const int n = nf * 16 + (lane & 15);
    const int kb = ks * 32 + (lane >> 4) * 8;
    short8v vh, vl;
    #pragma unroll
    for (int j = 0; j < 8; j++) {
        float wv = Wl[(size_t)(kb + j) * N + n];
        unsigned short hi = f2bf(wv);
        vh[j] = (short)hi;
        vl[j] = (short)f2bf(wv - bf2f(hi));
    }
    size_t o = (size_t)layer * K * N + ((size_t)(nf * KS + ks) * 64 + lane) * 8;
    *reinterpret_cast<short8v*>(oh + o) = vh;
    *reinterpret_cast<short8v*>(ol + o) = vl;
}

// ---------------- embed via split MFMA: h = x @ W_embed + b -----------------
__global__ __launch_bounds__(256) void embed_mfma_kernel(
    const float* __restrict__ x,
    const unsigned short* __restrict__ Weh, const unsigned short* __restrict__ Wel,
    const float* __restrict__ b, float* __restrict__ h)
{
    __shared__ __attribute__((aligned(16))) unsigned short xh[32 * 128];
    __shared__ __attribute__((aligned(16))) unsigned short xl[32 * 128];
    const int tid = threadIdx.x;
    const int lane = tid & 63, w = tid >> 6;
    const int lm = lane & 15, lq = lane >> 4;
    const int base = blockIdx.x * 32;
    {
        int row = tid >> 3, c0 = (tid & 7) * 16;
        const float4* p = reinterpret_cast<const float4*>(x + (size_t)(base + row) * 128 + c0);
        float4 u0 = p[0], u1 = p[1], u2 = p[2], u3 = p[3];
        float vals[16] = {u0.x,u0.y,u0.z,u0.w, u1.x,u1.y,u1.z,u1.w,
                          u2.x,u2.y,u2.z,u2.w, u3.x,u3.y,u3.z,u3.w};
        short8v vh0, vl0, vh1, vl1;
        #pragma unroll
        for (int j = 0; j < 8; j++) {
            unsigned short hi = f2bf(vals[j]);
            vh0[j] = (short)hi; vl0[j] = (short)f2bf(vals[j] - bf2f(hi));
            unsigned short hi1 = f2bf(vals[8 + j]);
            vh1[j] = (short)hi1; vl1[j] = (short)f2bf(vals[8 + j] - bf2f(hi1));
        }
        *reinterpret_cast<short8v*>(&xh[swz(row, c0, 128)]) = vh0;
        *reinterpret_cast<short8v*>(&xl[swz(row, c0, 128)]) = vl0;
        *reinterpret_cast<short8v*>(&xh[swz(row, c0 + 8, 128)]) = vh1;
        *reinterpret_cast<short8v*>(&xl[swz(row, c0 + 8, 128)]) = vl1;
    }
    __syncthreads();
    f32x4 acc0, acc1;
    {
        float bv = b[w * 16 + lm];
        acc0 = f32x4{bv, bv, bv, bv};
        acc1 = acc0;
    }
    #pragma unroll
    for (int ks = 0; ks < 4; ks++) {
        short8v a0h = *reinterpret_cast<const short8v*>(&xh[swz(lm, ks * 32 + lq * 8, 128)]);
        short8v a0l = *reinterpret_cast<const short8v*>(&xl[swz(lm, ks * 32 + lq * 8, 128)]);
        short8v a1h = *reinterpret_cast<const short8v*>(&xh[swz(16 + lm, ks * 32 + lq * 8, 128)]);
        short8v a1l = *reinterpret_cast<const short8v*>(&xl[swz(16 + lm, ks * 32 + lq * 8, 128)]);
        size_t bi = ((size_t)(w * 4 + ks) * 64 + lane) * 8;
        short8v bh = *reinterpret_cast<const short8v*>(Weh + bi);
        short8v bl = *reinterpret_cast<const short8v*>(Wel + bi);
        acc0 = MFMA16(a0h, bh, acc0); acc0 = MFMA16(a0l, bh, acc0); acc0 = MFMA16(a0h, bl, acc0);
        acc1 = MFMA16(a1h, bh, acc1); acc1 = MFMA16(a1l, bh, acc1); acc1 = MFMA16(a1h, bl, acc1);
    }
    #pragma unroll
    for (int r = 0; r < 4; r++) {
        h[(size_t)(base + lq * 4 + r) * 64 + w * 16 + lm] = acc0[r];
        h[(size_t)(base + 16 + lq * 4 + r) * 64 + w * 16 + lm] = acc1[r];
    }
}

// ---------------- fused MLP layer, split-bf16 MFMA --------------------------
// 64 nodes/block, 8 waves. m2 processed in 4 chunks of 128 cols (fused B+C).
__global__ __launch_bounds__(512) void layer_mfma_kernel(
    float* __restrict__ h, const int* __restrict__ cnt,
    const unsigned short* __restrict__ W1h, const unsigned short* __restrict__ W1l,
    const float* __restrict__ b1,
    const unsigned short* __restrict__ W2h, const unsigned short* __restrict__ W2l,
    const float* __restrict__ b2,
    const unsigned short* __restrict__ W3h, const unsigned short* __restrict__ W3l,
    const float* __restrict__ b3)
{
    __shared__ __attribute__((aligned(16))) unsigned short hsh[64 * 64];    // 8KB
    __shared__ __attribute__((aligned(16))) unsigned short hsl[64 * 64];    // 8KB
    __shared__ __attribute__((aligned(16))) unsigned short m1h_[64 * 256];  // 32KB
    __shared__ __attribute__((aligned(16))) unsigned short m1l_[64 * 256];  // 32KB
    __shared__ __attribute__((aligned(16))) unsigned short m2h_[64 * 128];  // 16KB
    __shared__ __attribute__((aligned(16))) unsigned short m2l_[64 * 128];  // 16KB
    const int tid = threadIdx.x;
    const int lane = tid & 63, w = tid >> 6;
    const int lm = lane & 15, lq = lane >> 4;
    const int mt = w >> 1, half = w & 1;
    const int base = blockIdx.x * 64;

    {   // stage 0: h tile (fp32) -> hi/lo bf16 planes
        int row = tid >> 3, c0 = (tid & 7) * 8;
        const float4* p = reinterpret_cast<const float4*>(h + (size_t)(base + row) * 64 + c0);
        float4 u0 = p[0], u1 = p[1];
        float vals[8] = {u0.x,u0.y,u0.z,u0.w, u1.x,u1.y,u1.z,u1.w};
        short8v vh, vl;
        #pragma unroll
        for (int j = 0; j < 8; j++) {
            unsigned short hi = f2bf(vals[j]);
            vh[j] = (short)hi;
            vl[j] = (short)f2bf(vals[j] - bf2f(hi));
        }
        *reinterpret_cast<short8v*>(&hsh[swz(row, c0, 64)]) = vh;
        *reinterpret_cast<short8v*>(&hsl[swz(row, c0, 64)]) = vl;
    }
    __syncthreads();

    // ---- stage A: m1 = relu(hs @ W1 + b1)  [64x256], wave: mt x (half*8+f) -
    {
        f32x4 acc[8];
        #pragma unroll
        for (int f = 0; f < 8; f++) {
            float bv = b1[(half * 8 + f) * 16 + lm];
            acc[f] = f32x4{bv, bv, bv, bv};
        }
        #pragma unroll
        for (int ks = 0; ks < 2; ks++) {
            short8v ah = *reinterpret_cast<const short8v*>(&hsh[swz(mt * 16 + lm, ks * 32 + lq * 8, 64)]);
            short8v al = *reinterpret_cast<const short8v*>(&hsl[swz(mt * 16 + lm, ks * 32 + lq * 8, 64)]);
            #pragma unroll
            for (int f = 0; f < 8; f++) {
                size_t bi = ((size_t)((half * 8 + f) * 2 + ks) * 64 + lane) * 8;
                short8v bh = *reinterpret_cast<const short8v*>(W1h + bi);
                short8v bl = *reinterpret_cast<const short8v*>(W1l + bi);
                acc[f] = MFMA16(ah, bh, acc[f]);
                acc[f] = MFMA16(al, bh, acc[f]);
                acc[f] = MFMA16(ah, bl, acc[f]);
            }
        }
        #pragma unroll
        for (int f = 0; f < 8; f++)
            #pragma unroll
            for (int r = 0; r < 4; r++) {
                int row = mt * 16 + lq * 4 + r;
                int col = (half * 8 + f) * 16 + lm;
                float v = fmaxf(acc[f][r], 0.f);
                unsigned short hi = f2bf(v);
                m1h_[swz(row, col, 256)] = hi;
                m1l_[swz(row, col, 256)] = f2bf(v - bf2f(hi));
            }
    }
    __syncthreads();

    // dh accumulators (persist across chunks): wave owns rows mt*16.., cols (half*2+f)*16..
    f32x4 dacc[2];
    #pragma unroll
    for (int f = 0; f < 2; f++) {
        float bv = b3[(half * 2 + f) * 16 + lm];
        dacc[f] = f32x4{bv, bv, bv, bv};
    }

    for (int c = 0; c < 4; ++c) {
        // ---- stage B: m2c = relu(m1 @ W2[:, c*128:+128] + b2) --------------
        {
            f32x4 acc[4];
            #pragma unroll
            for (int f = 0; f < 4; f++) {
                int nfg = c * 8 + half * 4 + f;
                float bv = b2[nfg * 16 + lm];
                acc[f] = f32x4{bv, bv, bv, bv};
            }
            #pragma unroll
            for (int ks = 0; ks < 8; ks++) {
                short8v ah = *reinterpret_cast<const short8v*>(&m1h_[swz(mt * 16 + lm, ks * 32 + lq * 8, 256)]);
                short8v al = *reinterpret_cast<const short8v*>(&m1l_[swz(mt * 16 + lm, ks * 32 + lq * 8, 256)]);
                #pragma unroll
                for (int f = 0; f < 4; f++) {
                    int nfg = c * 8 + half * 4 + f;
                    size_t bi = ((size_t)(nfg * 8 + ks) * 64 + lane) * 8;
                    short8v bh = *reinterpret_cast<const short8v*>(W2h + bi);
                    short8v bl = *reinterpret_cast<const short8v*>(W2l + bi);
                    acc[f] = MFMA16(ah, bh, acc[f]);
                    acc[f] = MFMA16(al, bh, acc[f]);
                    acc[f] = MFMA16(ah, bl, acc[f]);
                }
            }
            #pragma unroll
            for (int f = 0; f < 4; f++)
                #pragma unroll
                for (int r = 0; r < 4; r++) {
                    int row = mt * 16 + lq * 4 + r;
                    int coll = (half * 4 + f) * 16 + lm;
                    float v = fmaxf(acc[f][r], 0.f);
                    unsigned short hi = f2bf(v);
                    m2h_[swz(row, coll, 128)] = hi;
                    m2l_[swz(row, coll, 128)] = f2bf(v - bf2f(hi));
                }
        }
        __syncthreads();
        // ---- stage C partial: dacc += m2c @ W3[c*128:+128, :] --------------
        {
            #pragma unroll
            for (int kl = 0; kl < 4; kl++) {
                short8v ah = *reinterpret_cast<const short8v*>(&m2h_[swz(mt * 16 + lm, kl * 32 + lq * 8, 128)]);
                short8v al = *reinterpret_cast<const short8v*>(&m2l_[swz(mt * 16 + lm, kl * 32 + lq * 8, 128)]);
                #pragma unroll
                for (int f = 0; f < 2; f++) {
                    int nf = half * 2 + f;
                    int ksg = c * 4 + kl;
                    size_t bi = ((size_t)(nf * 16 + ksg) * 64 + lane) * 8;
                    short8v bh = *reinterpret_cast<const short8v*>(W3h + bi);
                    short8v bl = *reinterpret_cast<const short8v*>(W3l + bi);
                    dacc[f] = MFMA16(ah, bh, dacc[f]);
                    dacc[f] = MFMA16(al, bh, dacc[f]);
                    dacc[f] = MFMA16(ah, bl, dacc[f]);
                }
            }
        }
        __syncthreads();   // protect m2c before next chunk's writes
    }

    // ---- epilogue: h += cnt * dh ------------------------------------------
    #pragma unroll
    for (int r = 0; r < 4; r++) {
        int rr = base + mt * 16 + lq * 4 + r;
        float cv = (float)cnt[rr];
        #pragma unroll
        for (int f = 0; f < 2; f++) {
            size_t gi = (size_t)rr * 64 + (half * 2 + f) * 16 + lm;
            h[gi] = h[gi] + cv * dacc[f][r];
        }
    }
}

// ---------------- precompute score vectors (fp32) ---------------------------
__global__ __launch_bounds__(256) void prec_kernel(
    const float* __restrict__ q, const float* __restrict__ W_in,
    const float* __restrict__ b_in, const float* __restrict__ Wp,
    const float* __restrict__ bp, float* __restrict__ prec)
{
    __shared__ float qh_s[256];
    __shared__ float u_s[4 * 256];
    const int tid = threadIdx.x;
    {
        float acc = b_in[tid];
        for (int j = 0; j < 256; j++) acc += q[j] * W_in[j * 768 + tid];
        qh_s[tid] = acc * 0.125f;
    }
    __syncthreads();
    {
        #pragma unroll
        for (int hd = 0; hd < 4; hd++) {
            float a = 0.f;
            for (int d = 0; d < 64; d++)
                a += W_in[tid * 768 + 256 + hd * 64 + d] * qh_s[hd * 64 + d];
            u_s[hd * 256 + tid] = a;
        }
    }
    __syncthreads();
    {
        int hd = tid >> 6, i = tid & 63;
        float a = 0.f;
        for (int j = 0; j < 256; j++) a += Wp[i * 256 + j] * u_s[hd * 256 + j];
        prec[hd * 64 + i] = a;
    }
    if (tid < 4) {
        float a = 0.f;
        for (int j = 0; j < 256; j++) a += bp[j] * u_s[tid * 256 + j];
        for (int d = 0; d < 64; d++) a += b_in[256 + tid * 64 + d] * qh_s[tid * 64 + d];
        prec[256 + tid] = a;
    }
}

// ---------------- attention pooling (fp32) ----------------------------------
__global__ __launch_bounds__(64) void attnpool_kernel(
    const float* __restrict__ h, const float* __restrict__ prec,
    float* __restrict__ hw)
{
    __shared__ float hs[48 * 65];
    __shared__ float ss[4 * 64];
    __shared__ float ds_[4];
    __shared__ float wl[48 * 4];
    const int lane = threadIdx.x;
    const int g = blockIdx.x;
    #pragma unroll
    for (int hd = 0; hd < 4; hd++) ss[hd * 64 + lane] = prec[hd * 64 + lane];
    if (lane < 4) ds_[lane] = prec[256 + lane];
    for (int r = 0; r < 48; r++)
        hs[r * 65 + lane] = h[((size_t)g * 48 + r) * 64 + lane];
    __syncthreads();
    float sc[4] = {0.f, 0.f, 0.f, 0.f};
    if (lane < 48) {
        #pragma unroll
        for (int hd = 0; hd < 4; hd++) sc[hd] = ds_[hd];
        for (int c = 0; c < 64; c++) {
            float a = hs[lane * 65 + c];
            #pragma unroll
            for (int hd = 0; hd < 4; hd++) sc[hd] += a * ss[hd * 64 + c];
        }
    }
    #pragma unroll
    for (int hd = 0; hd < 4; hd++) {
        float v = (lane < 48) ? sc[hd] : -3.0e38f;
        #pragma unroll
        for (int m = 32; m >= 1; m >>= 1) v = fmaxf(v, __shfl_xor(v, m, 64));
        float e = (lane < 48) ? __expf(sc[hd] - v) : 0.f;
        float s = e;
        #pragma unroll
        for (int m = 32; m >= 1; m >>= 1) s += __shfl_xor(s, m, 64);
        if (lane < 48) wl[lane * 4 + hd] = e / s;
    }
    __syncthreads();
    float acc[4] = {0.f, 0.f, 0.f, 0.f};
    for (int n = 0; n < 48; n++) {
        float hv = hs[n * 65 + lane];
        #pragma unroll
        for (int hd = 0; hd < 4; hd++) acc[hd] += wl[n * 4 + hd] * hv;
    }
    #pragma unroll
    for (int hd = 0; hd < 4; hd++) hw[(size_t)g * 256 + hd * 64 + lane] = acc[hd];
}

// ---------------- tail (fp32) -----------------------------------------------
__global__ __launch_bounds__(256) void tail_kernel(
    const float* __restrict__ hw,
    const float* __restrict__ Wp, const float* __restrict__ bp,
    const float* __restrict__ W_in, const float* __restrict__ b_in,
    const float* __restrict__ W_out, const float* __restrict__ b_out,
    const float* __restrict__ Wh1, const float* __restrict__ bh1,
    const float* __restrict__ ln_g, const float* __restrict__ ln_b,
    const float* __restrict__ Wh2, const float* __restrict__ bh2,
    float* __restrict__ out)
{
    __shared__ float hw_s[8 * 256];
    __shared__ float hpw_s[8 * 1024];
    __shared__ float pooled_s[8 * 256];
    __shared__ float attn_s[8 * 256];
    __shared__ float t_s[8 * 256];
    __shared__ float mu_s[8], rs_s[8];
    const int tid = threadIdx.x;
    const int g0 = blockIdx.x * 8;
    #pragma unroll
    for (int r = 0; r < 8; r++)
        hw_s[r * 256 + tid] = hw[(size_t)g0 * 256 + r * 256 + tid];
    __syncthreads();
    {
        float acc[8][4];
        #pragma unroll
        for (int g = 0; g < 8; g++)
            #pragma unroll
            for (int hd = 0; hd < 4; hd++) acc[g][hd] = 0.f;
        for (int i = 0; i < 64; i++) {
            float wv = Wp[i * 256 + tid];
            #pragma unroll
            for (int g = 0; g < 8; g++)
                #pragma unroll
                for (int hd = 0; hd < 4; hd++)
                    acc[g][hd] += hw_s[g * 256 + hd * 64 + i] * wv;
        }
        float bpj = bp[tid];
        #pragma unroll
        for (int g = 0; g < 8; g++)
            #pragma unroll
            for (int hd = 0; hd < 4; hd++)
                hpw_s[g * 1024 + hd * 256 + tid] = acc[g][hd] + bpj;
    }
    __syncthreads();
    {
        const int hd = tid >> 6;
        float acc[8];
        #pragma unroll
        for (int g = 0; g < 8; g++) acc[g] = 0.f;
        for (int j = 0; j < 256; j++) {
            float wv = W_in[j * 768 + 512 + tid];
            #pragma unroll
            for (int g = 0; g < 8; g++)
                acc[g] += hpw_s[g * 1024 + hd * 256 + j] * wv;
        }
        float bb = b_in[512 + tid];
        #pragma unroll
        for (int g = 0; g < 8; g++) pooled_s[g * 256 + tid] = acc[g] + bb;
    }
    __syncthreads();
    {
        float acc[8];
        #pragma unroll
        for (int g = 0; g < 8; g++) acc[g] = 0.f;
        for (int j = 0; j < 256; j++) {
            float wv = W_out[j * 256 + tid];
            #pragma unroll
            for (int g = 0; g < 8; g++) acc[g] += pooled_s[g * 256 + j] * wv;
        }
        float bb = b_out[tid];
        #pragma unroll
        for (int g = 0; g < 8; g++)
            attn_s[g * 256 + tid] = fmaxf(acc[g] + bb, 0.f);
    }
    __syncthreads();
    {
        float acc[8];
        #pragma unroll
        for (int g = 0; g < 8; g++) acc[g] = 0.f;
        for (int j = 0; j < 256; j++) {
            float wv = Wh1[j * 256 + tid];
            #pragma unroll
            for (int g = 0; g < 8; g++) acc[g] += attn_s[g * 256 + j] * wv;
        }
        float bb = bh1[tid];
        #pragma unroll
        for (int g = 0; g < 8; g++)
            t_s[g * 256 + tid] = fmaxf(acc[g] + bb, 0.f);
    }
    __syncthreads();
    if (tid < 8) {
        float s = 0.f;
        for (int c = 0; c < 256; c++) s += t_s[tid * 256 + c];
        float mu = s * (1.f / 256.f);
        float v = 0.f;
        for (int c = 0; c < 256; c++) {
            float d = t_s[tid * 256 + c] - mu;
            v += d * d;
        }
        v *= (1.f / 256.f);
        mu_s[tid] = mu;
        rs_s[tid] = rsqrtf(v + 1e-5f);
    }
    __syncthreads();
    {
        float gg = ln_g[tid], bb = ln_b[tid];
        #pragma unroll
        for (int r = 0; r < 8; r++)
            t_s[r * 256 + tid] = (t_s[r * 256 + tid] - mu_s[r]) * rs_s[r] * gg + bb;
    }
    __syncthreads();
    {
        float acc[8][4];
        float4 bb = *reinterpret_cast<const float4*>(bh2 + tid * 4);
        #pragma unroll
        for (int g = 0; g < 8; g++) {
            acc[g][0] = bb.x; acc[g][1] = bb.y; acc[g][2] = bb.z; acc[g][3] = bb.w;
        }
        for (int j = 0; j < 256; j++) {
            float4 wv = *reinterpret_cast<const float4*>(Wh2 + (size_t)j * 1024 + tid * 4);
            #pragma unroll
            for (int g = 0; g < 8; g++) {
                float tv = t_s[g * 256 + j];
                acc[g][0] += tv * wv.x; acc[g][1] += tv * wv.y;
                acc[g][2] += tv * wv.z; acc[g][3] += tv * wv.w;
            }
        }
        #pragma unroll
        for (int g = 0; g < 8; g++)
            *reinterpret_cast<float4*>(out + (size_t)(g0 + g) * 1024 + tid * 4) =
                make_float4(acc[g][0], acc[g][1], acc[g][2], acc[g][3]);
    }
}

extern "C" void kernel_launch(void* const* d_in, const int* in_sizes, int n_in,
                              void* d_out, int out_size, void* d_ws, size_t ws_size,
                              hipStream_t stream) {
    const float* x       = (const float*)d_in[0];
    const int*   edge    = (const int*)d_in[1];
    const float* W_embed = (const float*)d_in[3];
    const float* b_embed = (const float*)d_in[4];
    const float* W1 = (const float*)d_in[5];
    const float* b1 = (const float*)d_in[6];
    const float* W2 = (const float*)d_in[7];
    const float* b2 = (const float*)d_in[8];
    const float* W3 = (const float*)d_in[9];
    const float* b3 = (const float*)d_in[10];
    const float* Wp = (const float*)d_in[11];
    const float* bp = (const float*)d_in[12];
    const float* q  = (const float*)d_in[13];
    const float* W_in  = (const float*)d_in[14];
    const float* b_in  = (const float*)d_in[15];
    const float* W_out = (const float*)d_in[16];
    const float* b_out = (const float*)d_in[17];
    const float* Wh1 = (const float*)d_in[18];
    const float* bh1 = (const float*)d_in[19];
    const float* ln_g = (const float*)d_in[20];
    const float* ln_b = (const float*)d_in[21];
    const float* Wh2 = (const float*)d_in[22];
    const float* bh2 = (const float*)d_in[23];
    float* out = (float*)d_out;

    char* ws = (char*)d_ws;
    int*   cnt  = (int*)(ws + 0);                           // 393216 B
    float* h    = (float*)(ws + 393216);                    // 25165824 B
    float* hw   = (float*)(ws + 25559040);                  // 2097152 B
    float* prec = (float*)(ws + 27656192);                  // 1040 B
    unsigned short* W1h = (unsigned short*)(ws + 27657232); // 196608
    unsigned short* W1l = (unsigned short*)(ws + 27853840); // 196608
    unsigned short* W2h = (unsigned short*)(ws + 28050448); // 1572864
    unsigned short* W2l = (unsigned short*)(ws + 29623312); // 1572864
    unsigned short* W3h = (unsigned short*)(ws + 31196176); // 393216
    unsigned short* W3l = (unsigned short*)(ws + 31589392); // 393216
    unsigned short* Weh = (unsigned short*)(ws + 31982608); // 16384
    unsigned short* Wel = (unsigned short*)(ws + 31998992); // 16384

    zero_cnt_kernel<<<N_NODES / 256, 256, 0, stream>>>(cnt);
    hist_kernel<<<N_EDGES / 256, 256, 0, stream>>>(edge, cnt);

    prep_frag_kernel<<<1 * (64 / 16) * (128 / 32), 64, 0, stream>>>(W_embed, Weh, Wel, 128, 64);
    prep_frag_kernel<<<6 * (256 / 16) * (64 / 32), 64, 0, stream>>>(W1, W1h, W1l, 64, 256);
    prep_frag_kernel<<<6 * (512 / 16) * (256 / 32), 64, 0, stream>>>(W2, W2h, W2l, 256, 512);
    prep_frag_kernel<<<6 * (64 / 16) * (512 / 32), 64, 0, stream>>>(W3, W3h, W3l, 512, 64);

    embed_mfma_kernel<<<N_NODES / 32, 256, 0, stream>>>(x, Weh, Wel, b_embed, h);
    for (int l = 0; l < N_LAYERS_; l++) {
        layer_mfma_kernel<<<N_NODES / 64, 512, 0, stream>>>(
            h, cnt,
            W1h + (size_t)l * EMB * HID,     W1l + (size_t)l * EMB * HID,     b1 + (size_t)l * HID,
            W2h + (size_t)l * HID * 2 * HID, W2l + (size_t)l * HID * 2 * HID, b2 + (size_t)l * 2 * HID,
            W3h + (size_t)l * 2 * HID * EMB, W3l + (size_t)l * 2 * HID * EMB, b3 + (size_t)l * EMB);
    }
    prec_kernel<<<1, 256, 0, stream>>>(q, W_in, b_in, Wp, bp, prec);
    attnpool_kernel<<<N_GRAPHS, 64, 0, stream>>>(h, prec, hw);
    tail_kernel<<<N_GRAPHS / 8, 256, 0, stream>>>(hw, Wp, bp, W_in, b_in,
                                                  W_out, b_out, Wh1, bh1,
                                                  ln_g, ln_b, Wh2, bh2, out);
}

// Round 4
// 918.665 us; speedup vs baseline: 11.6990x; 1.9690x over previous
//
#include <hip/hip_runtime.h>
#include <hip/hip_bf16.h>

#define N_NODES 98304
#define N_GRAPHS 2048
#define N_EDGES 393216
#define EMB 64
#define HID 256
#define N_LAYERS_ 6

typedef __attribute__((ext_vector_type(8))) short short8v;
typedef __attribute__((ext_vector_type(4))) float f32x4;
#define MFMA16(a, b, c) __builtin_amdgcn_mfma_f32_16x16x32_bf16(a, b, c, 0, 0, 0)

__device__ __forceinline__ unsigned short f2bf(float x) {
    unsigned int u = __float_as_uint(x);
    u = (u + 0x7fffu + ((u >> 16) & 1u)) >> 16;
    return (unsigned short)u;
}
__device__ __forceinline__ float bf2f(unsigned short h) {
    return __uint_as_float(((unsigned int)h) << 16);
}
// swizzled index in ushort units: XOR bits 3..5 (16B-slot id) with row&7
__device__ __forceinline__ int swz(int row, int col, int rowc) {
    return (row * rowc + col) ^ ((row & 7) << 3);
}

// ---------------- histogram of edge rows ----------------
__global__ __launch_bounds__(256) void zero_cnt_kernel(int* __restrict__ cnt) {
    int i = blockIdx.x * 256 + threadIdx.x;
    if (i < N_NODES) cnt[i] = 0;
}
__global__ __launch_bounds__(256) void hist_kernel(const int* __restrict__ row,
                                                   int* __restrict__ cnt) {
    int i = blockIdx.x * 256 + threadIdx.x;
    if (i < N_EDGES) atomicAdd(&cnt[row[i]], 1);
}

// ---------------- weight prep: fp32 [L][K][N] -> hi/lo bf16 MFMA B-frags ----
// frag layout per layer: [(nf*KS + ks)*64 + lane]*8 ; lane holds
// B[k = ks*32 + (lane>>4)*8 + j][n = nf*16 + (lane&15)]
__global__ __launch_bounds__(64) void prep_frag_kernel(
    const float* __restrict__ W, unsigned short* __restrict__ oh,
    unsigned short* __restrict__ ol, int K, int N)
{
    const int NF = N >> 4, KS = K >> 5;
    const int fpl = NF * KS;
    const int layer = blockIdx.x / fpl;
    const int fid = blockIdx.x % fpl;
    const int nf = fid / KS, ks = fid % KS;
    const int lane = threadIdx.x;
    const float* Wl = W + (size_t)layer * K * N;
    const int n = nf * 16 + (lane & 15);
    const int kb = ks * 32 + (lane >> 4) * 8;
    short8v vh, vl;
    #pragma unroll
    for (int j = 0; j < 8; j++) {
        float wv = Wl[(size_t)(kb + j) * N + n];
        unsigned short hi = f2bf(wv);
        vh[j] = (short)hi;
        vl[j] = (short)f2bf(wv - bf2f(hi));
    }
    size_t o = (size_t)layer * K * N + ((size_t)(nf * KS + ks) * 64 + lane) * 8;
    *reinterpret_cast<short8v*>(oh + o) = vh;
    *reinterpret_cast<short8v*>(ol + o) = vl;
}

// ---------------- embed via split MFMA: h = x @ W_embed + b -----------------
__global__ __launch_bounds__(256) void embed_mfma_kernel(
    const float* __restrict__ x,
    const unsigned short* __restrict__ Weh, const unsigned short* __restrict__ Wel,
    const float* __restrict__ b, float* __restrict__ h)
{
    __shared__ __attribute__((aligned(16))) unsigned short xh[32 * 128];
    __shared__ __attribute__((aligned(16))) unsigned short xl[32 * 128];
    const int tid = threadIdx.x;
    const int lane = tid & 63, w = tid >> 6;
    const int lm = lane & 15, lq = lane >> 4;
    const int base = blockIdx.x * 32;
    {
        int row = tid >> 3, c0 = (tid & 7) * 16;
        const float4* p = reinterpret_cast<const float4*>(x + (size_t)(base + row) * 128 + c0);
        float4 u0 = p[0], u1 = p[1], u2 = p[2], u3 = p[3];
        float vals[16] = {u0.x,u0.y,u0.z,u0.w, u1.x,u1.y,u1.z,u1.w,
                          u2.x,u2.y,u2.z,u2.w, u3.x,u3.y,u3.z,u3.w};
        short8v vh0, vl0, vh1, vl1;
        #pragma unroll
        for (int j = 0; j < 8; j++) {
            unsigned short hi = f2bf(vals[j]);
            vh0[j] = (short)hi; vl0[j] = (short)f2bf(vals[j] - bf2f(hi));
            unsigned short hi1 = f2bf(vals[8 + j]);
            vh1[j] = (short)hi1; vl1[j] = (short)f2bf(vals[8 + j] - bf2f(hi1));
        }
        *reinterpret_cast<short8v*>(&xh[swz(row, c0, 128)]) = vh0;
        *reinterpret_cast<short8v*>(&xl[swz(row, c0, 128)]) = vl0;
        *reinterpret_cast<short8v*>(&xh[swz(row, c0 + 8, 128)]) = vh1;
        *reinterpret_cast<short8v*>(&xl[swz(row, c0 + 8, 128)]) = vl1;
    }
    __syncthreads();
    f32x4 acc0, acc1;
    {
        float bv = b[w * 16 + lm];
        acc0 = f32x4{bv, bv, bv, bv};
        acc1 = acc0;
    }
    #pragma unroll
    for (int ks = 0; ks < 4; ks++) {
        short8v a0h = *reinterpret_cast<const short8v*>(&xh[swz(lm, ks * 32 + lq * 8, 128)]);
        short8v a0l = *reinterpret_cast<const short8v*>(&xl[swz(lm, ks * 32 + lq * 8, 128)]);
        short8v a1h = *reinterpret_cast<const short8v*>(&xh[swz(16 + lm, ks * 32 + lq * 8, 128)]);
        short8v a1l = *reinterpret_cast<const short8v*>(&xl[swz(16 + lm, ks * 32 + lq * 8, 128)]);
        size_t bi = ((size_t)(w * 4 + ks) * 64 + lane) * 8;
        short8v bh = *reinterpret_cast<const short8v*>(Weh + bi);
        short8v bl = *reinterpret_cast<const short8v*>(Wel + bi);
        acc0 = MFMA16(a0h, bh, acc0); acc0 = MFMA16(a0l, bh, acc0); acc0 = MFMA16(a0h, bl, acc0);
        acc1 = MFMA16(a1h, bh, acc1); acc1 = MFMA16(a1l, bh, acc1); acc1 = MFMA16(a1h, bl, acc1);
    }
    #pragma unroll
    for (int r = 0; r < 4; r++) {
        h[(size_t)(base + lq * 4 + r) * 64 + w * 16 + lm] = acc0[r];
        h[(size_t)(base + 16 + lq * 4 + r) * 64 + w * 16 + lm] = acc1[r];
    }
}

// ---------------- fused MLP layer, split-bf16 MFMA, v2 ----------------------
// 32 nodes/block, 8 waves, LDS 72KB -> 2 blocks/CU (4 waves/SIMD).
// Each wave register-blocks both 16-row M-tiles: 6 MFMAs per weight-frag pair.
__global__ __launch_bounds__(512, 4) void layer_mfma_kernel(
    float* __restrict__ h, const int* __restrict__ cnt,
    const unsigned short* __restrict__ W1h, const unsigned short* __restrict__ W1l,
    const float* __restrict__ b1,
    const unsigned short* __restrict__ W2h, const unsigned short* __restrict__ W2l,
    const float* __restrict__ b2,
    const unsigned short* __restrict__ W3h, const unsigned short* __restrict__ W3l,
    const float* __restrict__ b3)
{
    __shared__ __attribute__((aligned(16))) unsigned short hsh[32 * 64];    // 4KB
    __shared__ __attribute__((aligned(16))) unsigned short hsl[32 * 64];    // 4KB
    __shared__ __attribute__((aligned(16))) unsigned short m1h_[32 * 256];  // 16KB
    __shared__ __attribute__((aligned(16))) unsigned short m1l_[32 * 256];  // 16KB
    __shared__ __attribute__((aligned(16))) unsigned short m2h_[32 * 256];  // 16KB
    __shared__ __attribute__((aligned(16))) unsigned short m2l_[32 * 256];  // 16KB
    const int tid = threadIdx.x;
    const int lane = tid & 63, w = tid >> 6;
    const int lm = lane & 15, lq = lane >> 4;
    const int base = blockIdx.x * 32;

    {   // stage 0: h tile (fp32 32x64) -> hi/lo bf16 planes (b64 writes)
        int row = tid >> 4, c0 = (tid & 15) * 4;
        const float4 u = *reinterpret_cast<const float4*>(h + (size_t)(base + row) * 64 + c0);
        float vals[4] = {u.x, u.y, u.z, u.w};
        unsigned short vh[4], vl[4];
        #pragma unroll
        for (int j = 0; j < 4; j++) {
            vh[j] = f2bf(vals[j]);
            vl[j] = f2bf(vals[j] - bf2f(vh[j]));
        }
        int idx = swz(row, c0, 64);
        *reinterpret_cast<uint2*>(&hsh[idx]) = *reinterpret_cast<uint2*>(vh);
        *reinterpret_cast<uint2*>(&hsl[idx]) = *reinterpret_cast<uint2*>(vl);
    }
    __syncthreads();

    // ---- stage A: m1 = relu(hs @ W1 + b1)  [32x256]; wave w -> col frags {2w, 2w+1}
    {
        f32x4 acc[2][2];   // [f][m]
        #pragma unroll
        for (int f = 0; f < 2; f++) {
            float bv = b1[(2 * w + f) * 16 + lm];
            acc[f][0] = f32x4{bv, bv, bv, bv};
            acc[f][1] = acc[f][0];
        }
        #pragma unroll
        for (int ks = 0; ks < 2; ks++) {
            short8v ah0 = *reinterpret_cast<const short8v*>(&hsh[swz(lm, ks * 32 + lq * 8, 64)]);
            short8v al0 = *reinterpret_cast<const short8v*>(&hsl[swz(lm, ks * 32 + lq * 8, 64)]);
            short8v ah1 = *reinterpret_cast<const short8v*>(&hsh[swz(16 + lm, ks * 32 + lq * 8, 64)]);
            short8v al1 = *reinterpret_cast<const short8v*>(&hsl[swz(16 + lm, ks * 32 + lq * 8, 64)]);
            #pragma unroll
            for (int f = 0; f < 2; f++) {
                size_t bi = ((size_t)((2 * w + f) * 2 + ks) * 64 + lane) * 8;
                short8v bh = *reinterpret_cast<const short8v*>(W1h + bi);
                short8v bl = *reinterpret_cast<const short8v*>(W1l + bi);
                acc[f][0] = MFMA16(ah0, bh, acc[f][0]);
                acc[f][0] = MFMA16(al0, bh, acc[f][0]);
                acc[f][0] = MFMA16(ah0, bl, acc[f][0]);
                acc[f][1] = MFMA16(ah1, bh, acc[f][1]);
                acc[f][1] = MFMA16(al1, bh, acc[f][1]);
                acc[f][1] = MFMA16(ah1, bl, acc[f][1]);
            }
        }
        #pragma unroll
        for (int f = 0; f < 2; f++)
            #pragma unroll
            for (int m = 0; m < 2; m++)
                #pragma unroll
                for (int r = 0; r < 4; r++) {
                    int row = m * 16 + lq * 4 + r;
                    int col = (2 * w + f) * 16 + lm;
                    float v = fmaxf(acc[f][m][r], 0.f);
                    unsigned short hi = f2bf(v);
                    m1h_[swz(row, col, 256)] = hi;
                    m1l_[swz(row, col, 256)] = f2bf(v - bf2f(hi));
                }
    }
    __syncthreads();

    // persistent stage-C accumulators: wave -> nfc = w&3 (cols), kq = w>>2 (k-half)
    const int nfc = w & 3, kq = w >> 2;
    f32x4 dacc[2];
    if (kq == 0) {
        float bv = b3[nfc * 16 + lm];
        dacc[0] = f32x4{bv, bv, bv, bv};
    } else {
        dacc[0] = f32x4{0.f, 0.f, 0.f, 0.f};
    }
    dacc[1] = dacc[0];

    #pragma unroll
    for (int c = 0; c < 2; ++c) {
        // ---- stage B: m2c = relu(m1 @ W2[:, c*256:+256] + b2); wave -> frags {2w,2w+1}
        {
            f32x4 acc[2][2];
            #pragma unroll
            for (int f = 0; f < 2; f++) {
                float bv = b2[(c * 16 + 2 * w + f) * 16 + lm];
                acc[f][0] = f32x4{bv, bv, bv, bv};
                acc[f][1] = acc[f][0];
            }
            #pragma unroll
            for (int ks = 0; ks < 8; ks++) {
                short8v ah0 = *reinterpret_cast<const short8v*>(&m1h_[swz(lm, ks * 32 + lq * 8, 256)]);
                short8v al0 = *reinterpret_cast<const short8v*>(&m1l_[swz(lm, ks * 32 + lq * 8, 256)]);
                short8v ah1 = *reinterpret_cast<const short8v*>(&m1h_[swz(16 + lm, ks * 32 + lq * 8, 256)]);
                short8v al1 = *reinterpret_cast<const short8v*>(&m1l_[swz(16 + lm, ks * 32 + lq * 8, 256)]);
                #pragma unroll
                for (int f = 0; f < 2; f++) {
                    size_t bi = ((size_t)((c * 16 + 2 * w + f) * 8 + ks) * 64 + lane) * 8;
                    short8v bh = *reinterpret_cast<const short8v*>(W2h + bi);
                    short8v bl = *reinterpret_cast<const short8v*>(W2l + bi);
                    acc[f][0] = MFMA16(ah0, bh, acc[f][0]);
                    acc[f][0] = MFMA16(al0, bh, acc[f][0]);
                    acc[f][0] = MFMA16(ah0, bl, acc[f][0]);
                    acc[f][1] = MFMA16(ah1, bh, acc[f][1]);
                    acc[f][1] = MFMA16(al1, bh, acc[f][1]);
                    acc[f][1] = MFMA16(ah1, bl, acc[f][1]);
                }
            }
            #pragma unroll
            for (int f = 0; f < 2; f++)
                #pragma unroll
                for (int m = 0; m < 2; m++)
                    #pragma unroll
                    for (int r = 0; r < 4; r++) {
                        int row = m * 16 + lq * 4 + r;
                        int col = (2 * w + f) * 16 + lm;   // local col within chunk
                        float v = fmaxf(acc[f][m][r], 0.f);
                        unsigned short hi = f2bf(v);
                        m2h_[swz(row, col, 256)] = hi;
                        m2l_[swz(row, col, 256)] = f2bf(v - bf2f(hi));
                    }
        }
        __syncthreads();
        // ---- stage C partial: dacc += m2c[:, kq-half] @ W3[c*256 + ...] ----
        {
            #pragma unroll
            for (int kl = 0; kl < 4; kl++) {
                int ksl = kq * 4 + kl;
                short8v ah0 = *reinterpret_cast<const short8v*>(&m2h_[swz(lm, ksl * 32 + lq * 8, 256)]);
                short8v al0 = *reinterpret_cast<const short8v*>(&m2l_[swz(lm, ksl * 32 + lq * 8, 256)]);
                short8v ah1 = *reinterpret_cast<const short8v*>(&m2h_[swz(16 + lm, ksl * 32 + lq * 8, 256)]);
                short8v al1 = *reinterpret_cast<const short8v*>(&m2l_[swz(16 + lm, ksl * 32 + lq * 8, 256)]);
                int ksg = c * 8 + ksl;
                size_t bi = ((size_t)(nfc * 16 + ksg) * 64 + lane) * 8;
                short8v bh = *reinterpret_cast<const short8v*>(W3h + bi);
                short8v bl = *reinterpret_cast<const short8v*>(W3l + bi);
                dacc[0] = MFMA16(ah0, bh, dacc[0]);
                dacc[0] = MFMA16(al0, bh, dacc[0]);
                dacc[0] = MFMA16(ah0, bl, dacc[0]);
                dacc[1] = MFMA16(ah1, bh, dacc[1]);
                dacc[1] = MFMA16(al1, bh, dacc[1]);
                dacc[1] = MFMA16(ah1, bl, dacc[1]);
            }
        }
        __syncthreads();   // all C reads done before next chunk's B writes
    }

    // ---- combine kq halves via fp32 scratch (reuse m1 LDS), epilogue -------
    float* scr = reinterpret_cast<float*>(m1h_);   // 32*64 f32 = 8KB <= 16KB
    if (kq == 1) {
        #pragma unroll
        for (int m = 0; m < 2; m++)
            #pragma unroll
            for (int r = 0; r < 4; r++)
                scr[(m * 16 + lq * 4 + r) * 64 + nfc * 16 + lm] = dacc[m][r];
    }
    __syncthreads();
    if (kq == 0) {
        #pragma unroll
        for (int m = 0; m < 2; m++)
            #pragma unroll
            for (int r = 0; r < 4; r++) {
                int rr = base + m * 16 + lq * 4 + r;
                float dv = dacc[m][r] + scr[(m * 16 + lq * 4 + r) * 64 + nfc * 16 + lm];
                size_t gi = (size_t)rr * 64 + nfc * 16 + lm;
                h[gi] = h[gi] + (float)cnt[rr] * dv;
            }
    }
}

// ---------------- precompute score vectors (fp32) ---------------------------
__global__ __launch_bounds__(256) void prec_kernel(
    const float* __restrict__ q, const float* __restrict__ W_in,
    const float* __restrict__ b_in, const float* __restrict__ Wp,
    const float* __restrict__ bp, float* __restrict__ prec)
{
    __shared__ float qh_s[256];
    __shared__ float u_s[4 * 256];
    const int tid = threadIdx.x;
    {
        float acc = b_in[tid];
        for (int j = 0; j < 256; j++) acc += q[j] * W_in[j * 768 + tid];
        qh_s[tid] = acc * 0.125f;
    }
    __syncthreads();
    {
        #pragma unroll
        for (int hd = 0; hd < 4; hd++) {
            float a = 0.f;
            for (int d = 0; d < 64; d++)
                a += W_in[tid * 768 + 256 + hd * 64 + d] * qh_s[hd * 64 + d];
            u_s[hd * 256 + tid] = a;
        }
    }
    __syncthreads();
    {
        int hd = tid >> 6, i = tid & 63;
        float a = 0.f;
        for (int j = 0; j < 256; j++) a += Wp[i * 256 + j] * u_s[hd * 256 + j];
        prec[hd * 64 + i] = a;
    }
    if (tid < 4) {
        float a = 0.f;
        for (int j = 0; j < 256; j++) a += bp[j] * u_s[tid * 256 + j];
        for (int d = 0; d < 64; d++) a += b_in[256 + tid * 64 + d] * qh_s[tid * 64 + d];
        prec[256 + tid] = a;
    }
}

// ---------------- attention pooling (fp32) ----------------------------------
__global__ __launch_bounds__(64) void attnpool_kernel(
    const float* __restrict__ h, const float* __restrict__ prec,
    float* __restrict__ hw)
{
    __shared__ float hs[48 * 65];
    __shared__ float ss[4 * 64];
    __shared__ float ds_[4];
    __shared__ float wl[48 * 4];
    const int lane = threadIdx.x;
    const int g = blockIdx.x;
    #pragma unroll
    for (int hd = 0; hd < 4; hd++) ss[hd * 64 + lane] = prec[hd * 64 + lane];
    if (lane < 4) ds_[lane] = prec[256 + lane];
    for (int r = 0; r < 48; r++)
        hs[r * 65 + lane] = h[((size_t)g * 48 + r) * 64 + lane];
    __syncthreads();
    float sc[4] = {0.f, 0.f, 0.f, 0.f};
    if (lane < 48) {
        #pragma unroll
        for (int hd = 0; hd < 4; hd++) sc[hd] = ds_[hd];
        for (int c = 0; c < 64; c++) {
            float a = hs[lane * 65 + c];
            #pragma unroll
            for (int hd = 0; hd < 4; hd++) sc[hd] += a * ss[hd * 64 + c];
        }
    }
    #pragma unroll
    for (int hd = 0; hd < 4; hd++) {
        float v = (lane < 48) ? sc[hd] : -3.0e38f;
        #pragma unroll
        for (int m = 32; m >= 1; m >>= 1) v = fmaxf(v, __shfl_xor(v, m, 64));
        float e = (lane < 48) ? __expf(sc[hd] - v) : 0.f;
        float s = e;
        #pragma unroll
        for (int m = 32; m >= 1; m >>= 1) s += __shfl_xor(s, m, 64);
        if (lane < 48) wl[lane * 4 + hd] = e / s;
    }
    __syncthreads();
    float acc[4] = {0.f, 0.f, 0.f, 0.f};
    for (int n = 0; n < 48; n++) {
        float hv = hs[n * 65 + lane];
        #pragma unroll
        for (int hd = 0; hd < 4; hd++) acc[hd] += wl[n * 4 + hd] * hv;
    }
    #pragma unroll
    for (int hd = 0; hd < 4; hd++) hw[(size_t)g * 256 + hd * 64 + lane] = acc[hd];
}

// ---------------- tail (fp32) -----------------------------------------------
__global__ __launch_bounds__(256) void tail_kernel(
    const float* __restrict__ hw,
    const float* __restrict__ Wp, const float* __restrict__ bp,
    const float* __restrict__ W_in, const float* __restrict__ b_in,
    const float* __restrict__ W_out, const float* __restrict__ b_out,
    const float* __restrict__ Wh1, const float* __restrict__ bh1,
    const float* __restrict__ ln_g, const float* __restrict__ ln_b,
    const float* __restrict__ Wh2, const float* __restrict__ bh2,
    float* __restrict__ out)
{
    __shared__ float hw_s[8 * 256];
    __shared__ float hpw_s[8 * 1024];
    __shared__ float pooled_s[8 * 256];
    __shared__ float attn_s[8 * 256];
    __shared__ float t_s[8 * 256];
    __shared__ float mu_s[8], rs_s[8];
    const int tid = threadIdx.x;
    const int g0 = blockIdx.x * 8;
    #pragma unroll
    for (int r = 0; r < 8; r++)
        hw_s[r * 256 + tid] = hw[(size_t)g0 * 256 + r * 256 + tid];
    __syncthreads();
    {
        float acc[8][4];
        #pragma unroll
        for (int g = 0; g < 8; g++)
            #pragma unroll
            for (int hd = 0; hd < 4; hd++) acc[g][hd] = 0.f;
        for (int i = 0; i < 64; i++) {
            float wv = Wp[i * 256 + tid];
            #pragma unroll
            for (int g = 0; g < 8; g++)
                #pragma unroll
                for (int hd = 0; hd < 4; hd++)
                    acc[g][hd] += hw_s[g * 256 + hd * 64 + i] * wv;
        }
        float bpj = bp[tid];
        #pragma unroll
        for (int g = 0; g < 8; g++)
            #pragma unroll
            for (int hd = 0; hd < 4; hd++)
                hpw_s[g * 1024 + hd * 256 + tid] = acc[g][hd] + bpj;
    }
    __syncthreads();
    {
        const int hd = tid >> 6;
        float acc[8];
        #pragma unroll
        for (int g = 0; g < 8; g++) acc[g] = 0.f;
        for (int j = 0; j < 256; j++) {
            float wv = W_in[j * 768 + 512 + tid];
            #pragma unroll
            for (int g = 0; g < 8; g++)
                acc[g] += hpw_s[g * 1024 + hd * 256 + j] * wv;
        }
        float bb = b_in[512 + tid];
        #pragma unroll
        for (int g = 0; g < 8; g++) pooled_s[g * 256 + tid] = acc[g] + bb;
    }
    __syncthreads();
    {
        float acc[8];
        #pragma unroll
        for (int g = 0; g < 8; g++) acc[g] = 0.f;
        for (int j = 0; j < 256; j++) {
            float wv = W_out[j * 256 + tid];
            #pragma unroll
            for (int g = 0; g < 8; g++) acc[g] += pooled_s[g * 256 + j] * wv;
        }
        float bb = b_out[tid];
        #pragma unroll
        for (int g = 0; g < 8; g++)
            attn_s[g * 256 + tid] = fmaxf(acc[g] + bb, 0.f);
    }
    __syncthreads();
    {
        float acc[8];
        #pragma unroll
        for (int g = 0; g < 8; g++) acc[g] = 0.f;
        for (int j = 0; j < 256; j++) {
            float wv = Wh1[j * 256 + tid];
            #pragma unroll
            for (int g = 0; g < 8; g++) acc[g] += attn_s[g * 256 + j] * wv;
        }
        float bb = bh1[tid];
        #pragma unroll
        for (int g = 0; g < 8; g++)
            t_s[g * 256 + tid] = fmaxf(acc[g] + bb, 0.f);
    }
    __syncthreads();
    if (tid < 8) {
        float s = 0.f;
        for (int c = 0; c < 256; c++) s += t_s[tid * 256 + c];
        float mu = s * (1.f / 256.f);
        float v = 0.f;
        for (int c = 0; c < 256; c++) {
            float d = t_s[tid * 256 + c] - mu;
            v += d * d;
        }
        v *= (1.f / 256.f);
        mu_s[tid] = mu;
        rs_s[tid] = rsqrtf(v + 1e-5f);
    }
    __syncthreads();
    {
        float gg = ln_g[tid], bb = ln_b[tid];
        #pragma unroll
        for (int r = 0; r < 8; r++)
            t_s[r * 256 + tid] = (t_s[r * 256 + tid] - mu_s[r]) * rs_s[r] * gg + bb;
    }
    __syncthreads();
    {
        float acc[8][4];
        float4 bb = *reinterpret_cast<const float4*>(bh2 + tid * 4);
        #pragma unroll
        for (int g = 0; g < 8; g++) {
            acc[g][0] = bb.x; acc[g][1] = bb.y; acc[g][2] = bb.z; acc[g][3] = bb.w;
        }
        for (int j = 0; j < 256; j++) {
            float4 wv = *reinterpret_cast<const float4*>(Wh2 + (size_t)j * 1024 + tid * 4);
            #pragma unroll
            for (int g = 0; g < 8; g++) {
                float tv = t_s[g * 256 + j];
                acc[g][0] += tv * wv.x; acc[g][1] += tv * wv.y;
                acc[g][2] += tv * wv.z; acc[g][3] += tv * wv.w;
            }
        }
        #pragma unroll
        for (int g = 0; g < 8; g++)
            *reinterpret_cast<float4*>(out + (size_t)(g0 + g) * 1024 + tid * 4) =
                make_float4(acc[g][0], acc[g][1], acc[g][2], acc[g][3]);
    }
}

extern "C" void kernel_launch(void* const* d_in, const int* in_sizes, int n_in,
                              void* d_out, int out_size, void* d_ws, size_t ws_size,
                              hipStream_t stream) {
    const float* x       = (const float*)d_in[0];
    const int*   edge    = (const int*)d_in[1];
    const float* W_embed = (const float*)d_in[3];
    const float* b_embed = (const float*)d_in[4];
    const float* W1 = (const float*)d_in[5];
    const float* b1 = (const float*)d_in[6];
    const float* W2 = (const float*)d_in[7];
    const float* b2 = (const float*)d_in[8];
    const float* W3 = (const float*)d_in[9];
    const float* b3 = (const float*)d_in[10];
    const float* Wp = (const float*)d_in[11];
    const float* bp = (const float*)d_in[12];
    const float* q  = (const float*)d_in[13];
    const float* W_in  = (const float*)d_in[14];
    const float* b_in  = (const float*)d_in[15];
    const float* W_out = (const float*)d_in[16];
    const float* b_out = (const float*)d_in[17];
    const float* Wh1 = (const float*)d_in[18];
    const float* bh1 = (const float*)d_in[19];
    const float* ln_g = (const float*)d_in[20];
    const float* ln_b = (const float*)d_in[21];
    const float* Wh2 = (const float*)d_in[22];
    const float* bh2 = (const float*)d_in[23];
    float* out = (float*)d_out;

    char* ws = (char*)d_ws;
    int*   cnt  = (int*)(ws + 0);                           // 393216 B
    float* h    = (float*)(ws + 393216);                    // 25165824 B
    float* hw   = (float*)(ws + 25559040);                  // 2097152 B
    float* prec = (float*)(ws + 27656192);                  // 1040 B
    unsigned short* W1h = (unsigned short*)(ws + 27657232); // 196608
    unsigned short* W1l = (unsigned short*)(ws + 27853840); // 196608
    unsigned short* W2h = (unsigned short*)(ws + 28050448); // 1572864
    unsigned short* W2l = (unsigned short*)(ws + 29623312); // 1572864
    unsigned short* W3h = (unsigned short*)(ws + 31196176); // 393216
    unsigned short* W3l = (unsigned short*)(ws + 31589392); // 393216
    unsigned short* Weh = (unsigned short*)(ws + 31982608); // 16384
    unsigned short* Wel = (unsigned short*)(ws + 31998992); // 16384

    zero_cnt_kernel<<<N_NODES / 256, 256, 0, stream>>>(cnt);
    hist_kernel<<<N_EDGES / 256, 256, 0, stream>>>(edge, cnt);

    prep_frag_kernel<<<1 * (64 / 16) * (128 / 32), 64, 0, stream>>>(W_embed, Weh, Wel, 128, 64);
    prep_frag_kernel<<<6 * (256 / 16) * (64 / 32), 64, 0, stream>>>(W1, W1h, W1l, 64, 256);
    prep_frag_kernel<<<6 * (512 / 16) * (256 / 32), 64, 0, stream>>>(W2, W2h, W2l, 256, 512);
    prep_frag_kernel<<<6 * (64 / 16) * (512 / 32), 64, 0, stream>>>(W3, W3h, W3l, 512, 64);

    embed_mfma_kernel<<<N_NODES / 32, 256, 0, stream>>>(x, Weh, Wel, b_embed, h);
    for (int l = 0; l < N_LAYERS_; l++) {
        layer_mfma_kernel<<<N_NODES / 32, 512, 0, stream>>>(
            h, cnt,
            W1h + (size_t)l * EMB * HID,     W1l + (size_t)l * EMB * HID,     b1 + (size_t)l * HID,
            W2h + (size_t)l * HID * 2 * HID, W2l + (size_t)l * HID * 2 * HID, b2 + (size_t)l * 2 * HID,
            W3h + (size_t)l * 2 * HID * EMB, W3l + (size_t)l * 2 * HID * EMB, b3 + (size_t)l * EMB);
    }
    prec_kernel<<<1, 256, 0, stream>>>(q, W_in, b_in, Wp, bp, prec);
    attnpool_kernel<<<N_GRAPHS, 64, 0, stream>>>(h, prec, hw);
    tail_kernel<<<N_GRAPHS / 8, 256, 0, stream>>>(hw, Wp, bp, W_in, b_in,
                                                  W_out, b_out, Wh1, bh1,
                                                  ln_g, ln_b, Wh2, bh2, out);
}

// Round 5
// 882.248 us; speedup vs baseline: 12.1819x; 1.0413x over previous
//
#include <hip/hip_runtime.h>
#include <hip/hip_bf16.h>

#define N_NODES 98304
#define N_GRAPHS 2048
#define N_EDGES 393216
#define EMB 64
#define HID 256
#define N_LAYERS_ 6

typedef __attribute__((ext_vector_type(8))) short short8v;
typedef __attribute__((ext_vector_type(4))) float f32x4;
#define MFMA16(a, b, c) __builtin_amdgcn_mfma_f32_16x16x32_bf16(a, b, c, 0, 0, 0)

__device__ __forceinline__ unsigned short f2bf(float x) {
    unsigned int u = __float_as_uint(x);
    u = (u + 0x7fffu + ((u >> 16) & 1u)) >> 16;
    return (unsigned short)u;
}
__device__ __forceinline__ float bf2f(unsigned short h) {
    return __uint_as_float(((unsigned int)h) << 16);
}
// swizzled index in ushort units: XOR bits 3..5 (16B-slot id) with row&7
__device__ __forceinline__ int swz(int row, int col, int rowc) {
    return (row * rowc + col) ^ ((row & 7) << 3);
}

// ---------------- histogram of edge rows ----------------
__global__ __launch_bounds__(256) void zero_cnt_kernel(int* __restrict__ cnt) {
    int i = blockIdx.x * 256 + threadIdx.x;
    if (i < N_NODES) cnt[i] = 0;
}
__global__ __launch_bounds__(256) void hist_kernel(const int* __restrict__ row,
                                                   int* __restrict__ cnt) {
    int i = blockIdx.x * 256 + threadIdx.x;
    if (i < N_EDGES) atomicAdd(&cnt[row[i]], 1);
}

// ---------------- weight prep: fp32 [L][K][N] -> hi/lo bf16 MFMA B-frags ----
// frag layout per layer: [(nf*KS + ks)*64 + lane]*8 ; lane holds
// B[k = ks*32 + (lane>>4)*8 + j][n = nf*16 + (lane&15)]
__global__ __launch_bounds__(64) void prep_frag_kernel(
    const float* __restrict__ W, unsigned short* __restrict__ oh,
    unsigned short* __restrict__ ol, int K, int N)
{
    const int NF = N >> 4, KS = K >> 5;
    const int fpl = NF * KS;
    const int layer = blockIdx.x / fpl;
    const int fid = blockIdx.x % fpl;
    const int nf = fid / KS, ks = fid % KS;
    const int lane = threadIdx.x;
    const float* Wl = W + (size_t)layer * K * N;
    const int n = nf * 16 + (lane & 15);
    const int kb = ks * 32 + (lane >> 4) * 8;
    short8v vh, vl;
    #pragma unroll
    for (int j = 0; j < 8; j++) {
        float wv = Wl[(size_t)(kb + j) * N + n];
        unsigned short hi = f2bf(wv);
        vh[j] = (short)hi;
        vl[j] = (short)f2bf(wv - bf2f(hi));
    }
    size_t o = (size_t)layer * K * N + ((size_t)(nf * KS + ks) * 64 + lane) * 8;
    *reinterpret_cast<short8v*>(oh + o) = vh;
    *reinterpret_cast<short8v*>(ol + o) = vl;
}

// ---------------- G = per-head (Wp @ Wv) fold + d vector --------------------
// G[q][p] = (q>>6==p>>6) ? sum_j Wp[q&63][j] * W_in[j][512+p] : 0
// d[p] = sum_j bp[j]*W_in[j][512+p] + b_in[512+p]
__global__ __launch_bounds__(256) void gbuild_kernel(
    const float* __restrict__ Wp, const float* __restrict__ bp,
    const float* __restrict__ W_in, const float* __restrict__ b_in,
    float* __restrict__ Gm, float* __restrict__ Gd)
{
    const int idx = blockIdx.x * 256 + threadIdx.x;
    const int q = idx >> 8, p = idx & 255;
    float s = 0.f;
    if ((q >> 6) == (p >> 6)) {
        const float* wr = Wp + (q & 63) * 256;
        for (int j = 0; j < 256; j++) s += wr[j] * W_in[j * 768 + 512 + p];
    }
    Gm[q * 256 + p] = s;
    if (blockIdx.x == 0) {
        const int pp = threadIdx.x;
        float dsum = b_in[512 + pp];
        for (int j = 0; j < 256; j++) dsum += bp[j] * W_in[j * 768 + 512 + pp];
        Gd[pp] = dsum;
    }
}

// ---------------- embed via split MFMA: h = x @ W_embed + b -----------------
__global__ __launch_bounds__(256) void embed_mfma_kernel(
    const float* __restrict__ x,
    const unsigned short* __restrict__ Weh, const unsigned short* __restrict__ Wel,
    const float* __restrict__ b, float* __restrict__ h)
{
    __shared__ __attribute__((aligned(16))) unsigned short xh[32 * 128];
    __shared__ __attribute__((aligned(16))) unsigned short xl[32 * 128];
    const int tid = threadIdx.x;
    const int lane = tid & 63, w = tid >> 6;
    const int lm = lane & 15, lq = lane >> 4;
    const int base = blockIdx.x * 32;
    {
        int row = tid >> 3, c0 = (tid & 7) * 16;
        const float4* p = reinterpret_cast<const float4*>(x + (size_t)(base + row) * 128 + c0);
        float4 u0 = p[0], u1 = p[1], u2 = p[2], u3 = p[3];
        float vals[16] = {u0.x,u0.y,u0.z,u0.w, u1.x,u1.y,u1.z,u1.w,
                          u2.x,u2.y,u2.z,u2.w, u3.x,u3.y,u3.z,u3.w};
        short8v vh0, vl0, vh1, vl1;
        #pragma unroll
        for (int j = 0; j < 8; j++) {
            unsigned short hi = f2bf(vals[j]);
            vh0[j] = (short)hi; vl0[j] = (short)f2bf(vals[j] - bf2f(hi));
            unsigned short hi1 = f2bf(vals[8 + j]);
            vh1[j] = (short)hi1; vl1[j] = (short)f2bf(vals[8 + j] - bf2f(hi1));
        }
        *reinterpret_cast<short8v*>(&xh[swz(row, c0, 128)]) = vh0;
        *reinterpret_cast<short8v*>(&xl[swz(row, c0, 128)]) = vl0;
        *reinterpret_cast<short8v*>(&xh[swz(row, c0 + 8, 128)]) = vh1;
        *reinterpret_cast<short8v*>(&xl[swz(row, c0 + 8, 128)]) = vl1;
    }
    __syncthreads();
    f32x4 acc0, acc1;
    {
        float bv = b[w * 16 + lm];
        acc0 = f32x4{bv, bv, bv, bv};
        acc1 = acc0;
    }
    #pragma unroll
    for (int ks = 0; ks < 4; ks++) {
        short8v a0h = *reinterpret_cast<const short8v*>(&xh[swz(lm, ks * 32 + lq * 8, 128)]);
        short8v a0l = *reinterpret_cast<const short8v*>(&xl[swz(lm, ks * 32 + lq * 8, 128)]);
        short8v a1h = *reinterpret_cast<const short8v*>(&xh[swz(16 + lm, ks * 32 + lq * 8, 128)]);
        short8v a1l = *reinterpret_cast<const short8v*>(&xl[swz(16 + lm, ks * 32 + lq * 8, 128)]);
        size_t bi = ((size_t)(w * 4 + ks) * 64 + lane) * 8;
        short8v bh = *reinterpret_cast<const short8v*>(Weh + bi);
        short8v bl = *reinterpret_cast<const short8v*>(Wel + bi);
        acc0 = MFMA16(a0h, bh, acc0); acc0 = MFMA16(a0l, bh, acc0); acc0 = MFMA16(a0h, bl, acc0);
        acc1 = MFMA16(a1h, bh, acc1); acc1 = MFMA16(a1l, bh, acc1); acc1 = MFMA16(a1h, bl, acc1);
    }
    #pragma unroll
    for (int r = 0; r < 4; r++) {
        h[(size_t)(base + lq * 4 + r) * 64 + w * 16 + lm] = acc0[r];
        h[(size_t)(base + 16 + lq * 4 + r) * 64 + w * 16 + lm] = acc1[r];
    }
}

// ---------------- fused MLP layer, split-bf16 MFMA (unchanged from R4) ------
__global__ __launch_bounds__(512, 4) void layer_mfma_kernel(
    float* __restrict__ h, const int* __restrict__ cnt,
    const unsigned short* __restrict__ W1h, const unsigned short* __restrict__ W1l,
    const float* __restrict__ b1,
    const unsigned short* __restrict__ W2h, const unsigned short* __restrict__ W2l,
    const float* __restrict__ b2,
    const unsigned short* __restrict__ W3h, const unsigned short* __restrict__ W3l,
    const float* __restrict__ b3)
{
    __shared__ __attribute__((aligned(16))) unsigned short hsh[32 * 64];
    __shared__ __attribute__((aligned(16))) unsigned short hsl[32 * 64];
    __shared__ __attribute__((aligned(16))) unsigned short m1h_[32 * 256];
    __shared__ __attribute__((aligned(16))) unsigned short m1l_[32 * 256];
    __shared__ __attribute__((aligned(16))) unsigned short m2h_[32 * 256];
    __shared__ __attribute__((aligned(16))) unsigned short m2l_[32 * 256];
    const int tid = threadIdx.x;
    const int lane = tid & 63, w = tid >> 6;
    const int lm = lane & 15, lq = lane >> 4;
    const int base = blockIdx.x * 32;

    {
        int row = tid >> 4, c0 = (tid & 15) * 4;
        const float4 u = *reinterpret_cast<const float4*>(h + (size_t)(base + row) * 64 + c0);
        float vals[4] = {u.x, u.y, u.z, u.w};
        unsigned short vh[4], vl[4];
        #pragma unroll
        for (int j = 0; j < 4; j++) {
            vh[j] = f2bf(vals[j]);
            vl[j] = f2bf(vals[j] - bf2f(vh[j]));
        }
        int idx = swz(row, c0, 64);
        *reinterpret_cast<uint2*>(&hsh[idx]) = *reinterpret_cast<uint2*>(vh);
        *reinterpret_cast<uint2*>(&hsl[idx]) = *reinterpret_cast<uint2*>(vl);
    }
    __syncthreads();

    {
        f32x4 acc[2][2];
        #pragma unroll
        for (int f = 0; f < 2; f++) {
            float bv = b1[(2 * w + f) * 16 + lm];
            acc[f][0] = f32x4{bv, bv, bv, bv};
            acc[f][1] = acc[f][0];
        }
        #pragma unroll
        for (int ks = 0; ks < 2; ks++) {
            short8v ah0 = *reinterpret_cast<const short8v*>(&hsh[swz(lm, ks * 32 + lq * 8, 64)]);
            short8v al0 = *reinterpret_cast<const short8v*>(&hsl[swz(lm, ks * 32 + lq * 8, 64)]);
            short8v ah1 = *reinterpret_cast<const short8v*>(&hsh[swz(16 + lm, ks * 32 + lq * 8, 64)]);
            short8v al1 = *reinterpret_cast<const short8v*>(&hsl[swz(16 + lm, ks * 32 + lq * 8, 64)]);
            #pragma unroll
            for (int f = 0; f < 2; f++) {
                size_t bi = ((size_t)((2 * w + f) * 2 + ks) * 64 + lane) * 8;
                short8v bh = *reinterpret_cast<const short8v*>(W1h + bi);
                short8v bl = *reinterpret_cast<const short8v*>(W1l + bi);
                acc[f][0] = MFMA16(ah0, bh, acc[f][0]);
                acc[f][0] = MFMA16(al0, bh, acc[f][0]);
                acc[f][0] = MFMA16(ah0, bl, acc[f][0]);
                acc[f][1] = MFMA16(ah1, bh, acc[f][1]);
                acc[f][1] = MFMA16(al1, bh, acc[f][1]);
                acc[f][1] = MFMA16(ah1, bl, acc[f][1]);
            }
        }
        #pragma unroll
        for (int f = 0; f < 2; f++)
            #pragma unroll
            for (int m = 0; m < 2; m++)
                #pragma unroll
                for (int r = 0; r < 4; r++) {
                    int row = m * 16 + lq * 4 + r;
                    int col = (2 * w + f) * 16 + lm;
                    float v = fmaxf(acc[f][m][r], 0.f);
                    unsigned short hi = f2bf(v);
                    m1h_[swz(row, col, 256)] = hi;
                    m1l_[swz(row, col, 256)] = f2bf(v - bf2f(hi));
                }
    }
    __syncthreads();

    const int nfc = w & 3, kq = w >> 2;
    f32x4 dacc[2];
    if (kq == 0) {
        float bv = b3[nfc * 16 + lm];
        dacc[0] = f32x4{bv, bv, bv, bv};
    } else {
        dacc[0] = f32x4{0.f, 0.f, 0.f, 0.f};
    }
    dacc[1] = dacc[0];

    #pragma unroll
    for (int c = 0; c < 2; ++c) {
        {
            f32x4 acc[2][2];
            #pragma unroll
            for (int f = 0; f < 2; f++) {
                float bv = b2[(c * 16 + 2 * w + f) * 16 + lm];
                acc[f][0] = f32x4{bv, bv, bv, bv};
                acc[f][1] = acc[f][0];
            }
            #pragma unroll
            for (int ks = 0; ks < 8; ks++) {
                short8v ah0 = *reinterpret_cast<const short8v*>(&m1h_[swz(lm, ks * 32 + lq * 8, 256)]);
                short8v al0 = *reinterpret_cast<const short8v*>(&m1l_[swz(lm, ks * 32 + lq * 8, 256)]);
                short8v ah1 = *reinterpret_cast<const short8v*>(&m1h_[swz(16 + lm, ks * 32 + lq * 8, 256)]);
                short8v al1 = *reinterpret_cast<const short8v*>(&m1l_[swz(16 + lm, ks * 32 + lq * 8, 256)]);
                #pragma unroll
                for (int f = 0; f < 2; f++) {
                    size_t bi = ((size_t)((c * 16 + 2 * w + f) * 8 + ks) * 64 + lane) * 8;
                    short8v bh = *reinterpret_cast<const short8v*>(W2h + bi);
                    short8v bl = *reinterpret_cast<const short8v*>(W2l + bi);
                    acc[f][0] = MFMA16(ah0, bh, acc[f][0]);
                    acc[f][0] = MFMA16(al0, bh, acc[f][0]);
                    acc[f][0] = MFMA16(ah0, bl, acc[f][0]);
                    acc[f][1] = MFMA16(ah1, bh, acc[f][1]);
                    acc[f][1] = MFMA16(al1, bh, acc[f][1]);
                    acc[f][1] = MFMA16(ah1, bl, acc[f][1]);
                }
            }
            #pragma unroll
            for (int f = 0; f < 2; f++)
                #pragma unroll
                for (int m = 0; m < 2; m++)
                    #pragma unroll
                    for (int r = 0; r < 4; r++) {
                        int row = m * 16 + lq * 4 + r;
                        int col = (2 * w + f) * 16 + lm;
                        float v = fmaxf(acc[f][m][r], 0.f);
                        unsigned short hi = f2bf(v);
                        m2h_[swz(row, col, 256)] = hi;
                        m2l_[swz(row, col, 256)] = f2bf(v - bf2f(hi));
                    }
        }
        __syncthreads();
        {
            #pragma unroll
            for (int kl = 0; kl < 4; kl++) {
                int ksl = kq * 4 + kl;
                short8v ah0 = *reinterpret_cast<const short8v*>(&m2h_[swz(lm, ksl * 32 + lq * 8, 256)]);
                short8v al0 = *reinterpret_cast<const short8v*>(&m2l_[swz(lm, ksl * 32 + lq * 8, 256)]);
                short8v ah1 = *reinterpret_cast<const short8v*>(&m2h_[swz(16 + lm, ksl * 32 + lq * 8, 256)]);
                short8v al1 = *reinterpret_cast<const short8v*>(&m2l_[swz(16 + lm, ksl * 32 + lq * 8, 256)]);
                int ksg = c * 8 + ksl;
                size_t bi = ((size_t)(nfc * 16 + ksg) * 64 + lane) * 8;
                short8v bh = *reinterpret_cast<const short8v*>(W3h + bi);
                short8v bl = *reinterpret_cast<const short8v*>(W3l + bi);
                dacc[0] = MFMA16(ah0, bh, dacc[0]);
                dacc[0] = MFMA16(al0, bh, dacc[0]);
                dacc[0] = MFMA16(ah0, bl, dacc[0]);
                dacc[1] = MFMA16(ah1, bh, dacc[1]);
                dacc[1] = MFMA16(al1, bh, dacc[1]);
                dacc[1] = MFMA16(ah1, bl, dacc[1]);
            }
        }
        __syncthreads();
    }

    float* scr = reinterpret_cast<float*>(m1h_);
    if (kq == 1) {
        #pragma unroll
        for (int m = 0; m < 2; m++)
            #pragma unroll
            for (int r = 0; r < 4; r++)
                scr[(m * 16 + lq * 4 + r) * 64 + nfc * 16 + lm] = dacc[m][r];
    }
    __syncthreads();
    if (kq == 0) {
        #pragma unroll
        for (int m = 0; m < 2; m++)
            #pragma unroll
            for (int r = 0; r < 4; r++) {
                int rr = base + m * 16 + lq * 4 + r;
                float dv = dacc[m][r] + scr[(m * 16 + lq * 4 + r) * 64 + nfc * 16 + lm];
                size_t gi = (size_t)rr * 64 + nfc * 16 + lm;
                h[gi] = h[gi] + (float)cnt[rr] * dv;
            }
    }
}

// ---------------- precompute score vectors (fp32) ---------------------------
__global__ __launch_bounds__(256) void prec_kernel(
    const float* __restrict__ q, const float* __restrict__ W_in,
    const float* __restrict__ b_in, const float* __restrict__ Wp,
    const float* __restrict__ bp, float* __restrict__ prec)
{
    __shared__ float qh_s[256];
    __shared__ float u_s[4 * 256];
    const int tid = threadIdx.x;
    {
        float acc = b_in[tid];
        for (int j = 0; j < 256; j++) acc += q[j] * W_in[j * 768 + tid];
        qh_s[tid] = acc * 0.125f;
    }
    __syncthreads();
    {
        #pragma unroll
        for (int hd = 0; hd < 4; hd++) {
            float a = 0.f;
            for (int d = 0; d < 64; d++)
                a += W_in[tid * 768 + 256 + hd * 64 + d] * qh_s[hd * 64 + d];
            u_s[hd * 256 + tid] = a;
        }
    }
    __syncthreads();
    {
        int hd = tid >> 6, i = tid & 63;
        float a = 0.f;
        for (int j = 0; j < 256; j++) a += Wp[i * 256 + j] * u_s[hd * 256 + j];
        prec[hd * 64 + i] = a;
    }
    if (tid < 4) {
        float a = 0.f;
        for (int j = 0; j < 256; j++) a += bp[j] * u_s[tid * 256 + j];
        for (int d = 0; d < 64; d++) a += b_in[256 + tid * 64 + d] * qh_s[tid * 64 + d];
        prec[256 + tid] = a;
    }
}

// ---------------- attention pooling (fp32) ----------------------------------
__global__ __launch_bounds__(64) void attnpool_kernel(
    const float* __restrict__ h, const float* __restrict__ prec,
    float* __restrict__ hw)
{
    __shared__ float hs[48 * 65];
    __shared__ float ss[4 * 64];
    __shared__ float ds_[4];
    __shared__ float wl[48 * 4];
    const int lane = threadIdx.x;
    const int g = blockIdx.x;
    #pragma unroll
    for (int hd = 0; hd < 4; hd++) ss[hd * 64 + lane] = prec[hd * 64 + lane];
    if (lane < 4) ds_[lane] = prec[256 + lane];
    for (int r = 0; r < 48; r++)
        hs[r * 65 + lane] = h[((size_t)g * 48 + r) * 64 + lane];
    __syncthreads();
    float sc[4] = {0.f, 0.f, 0.f, 0.f};
    if (lane < 48) {
        #pragma unroll
        for (int hd = 0; hd < 4; hd++) sc[hd] = ds_[hd];
        for (int c = 0; c < 64; c++) {
            float a = hs[lane * 65 + c];
            #pragma unroll
            for (int hd = 0; hd < 4; hd++) sc[hd] += a * ss[hd * 64 + c];
        }
    }
    #pragma unroll
    for (int hd = 0; hd < 4; hd++) {
        float v = (lane < 48) ? sc[hd] : -3.0e38f;
        #pragma unroll
        for (int m = 32; m >= 1; m >>= 1) v = fmaxf(v, __shfl_xor(v, m, 64));
        float e = (lane < 48) ? __expf(sc[hd] - v) : 0.f;
        float s = e;
        #pragma unroll
        for (int m = 32; m >= 1; m >>= 1) s += __shfl_xor(s, m, 64);
        if (lane < 48) wl[lane * 4 + hd] = e / s;
    }
    __syncthreads();
    float acc[4] = {0.f, 0.f, 0.f, 0.f};
    for (int n = 0; n < 48; n++) {
        float hv = hs[n * 65 + lane];
        #pragma unroll
        for (int hd = 0; hd < 4; hd++) acc[hd] += wl[n * 4 + hd] * hv;
    }
    #pragma unroll
    for (int hd = 0; hd < 4; hd++) hw[(size_t)g * 256 + hd * 64 + lane] = acc[hd];
}

// ---------------- tail stage helper: [32x256] @ [256x256] split-bf16 --------
__device__ __forceinline__ void tail_stage(
    const unsigned short* __restrict__ inh, const unsigned short* __restrict__ inl,
    const unsigned short* __restrict__ wh, const unsigned short* __restrict__ wl,
    const float* __restrict__ bias, const bool do_relu,
    unsigned short* __restrict__ oth, unsigned short* __restrict__ otl,
    float* __restrict__ tf32,
    const int w, const int lane, const int lm, const int lq)
{
    f32x4 acc[2][2];
    #pragma unroll
    for (int f = 0; f < 2; f++) {
        float bv = bias[(2 * w + f) * 16 + lm];
        acc[f][0] = f32x4{bv, bv, bv, bv};
        acc[f][1] = acc[f][0];
    }
    #pragma unroll
    for (int ks = 0; ks < 8; ks++) {
        short8v ah0 = *reinterpret_cast<const short8v*>(&inh[swz(lm, ks * 32 + lq * 8, 256)]);
        short8v al0 = *reinterpret_cast<const short8v*>(&inl[swz(lm, ks * 32 + lq * 8, 256)]);
        short8v ah1 = *reinterpret_cast<const short8v*>(&inh[swz(16 + lm, ks * 32 + lq * 8, 256)]);
        short8v al1 = *reinterpret_cast<const short8v*>(&inl[swz(16 + lm, ks * 32 + lq * 8, 256)]);
        #pragma unroll
        for (int f = 0; f < 2; f++) {
            size_t bi = ((size_t)((2 * w + f) * 8 + ks) * 64 + lane) * 8;
            short8v bh = *reinterpret_cast<const short8v*>(wh + bi);
            short8v bl = *reinterpret_cast<const short8v*>(wl + bi);
            acc[f][0] = MFMA16(ah0, bh, acc[f][0]);
            acc[f][0] = MFMA16(al0, bh, acc[f][0]);
            acc[f][0] = MFMA16(ah0, bl, acc[f][0]);
            acc[f][1] = MFMA16(ah1, bh, acc[f][1]);
            acc[f][1] = MFMA16(al1, bh, acc[f][1]);
            acc[f][1] = MFMA16(ah1, bl, acc[f][1]);
        }
    }
    #pragma unroll
    for (int f = 0; f < 2; f++)
        #pragma unroll
        for (int m = 0; m < 2; m++)
            #pragma unroll
            for (int r = 0; r < 4; r++) {
                int row = m * 16 + lq * 4 + r;
                int col = (2 * w + f) * 16 + lm;
                float v = acc[f][m][r];
                if (do_relu) v = fmaxf(v, 0.f);
                if (tf32) {
                    tf32[row * 256 + col] = v;
                } else {
                    unsigned short hi = f2bf(v);
                    oth[swz(row, col, 256)] = hi;
                    otl[swz(row, col, 256)] = f2bf(v - bf2f(hi));
                }
            }
}

// ---------------- fused MFMA tail: pooled->attn->t->LN->out -----------------
// 32 graphs/block, 64 blocks, 512 threads; ping-pong 32KB LDS buffers.
__global__ __launch_bounds__(512, 4) void tail_mfma_kernel(
    const float* __restrict__ hw,
    const unsigned short* __restrict__ Gh, const unsigned short* __restrict__ Gl,
    const float* __restrict__ Gd,
    const unsigned short* __restrict__ Woh, const unsigned short* __restrict__ Wol,
    const float* __restrict__ b_out,
    const unsigned short* __restrict__ Wh1h, const unsigned short* __restrict__ Wh1l,
    const float* __restrict__ bh1,
    const float* __restrict__ ln_g, const float* __restrict__ ln_b,
    const unsigned short* __restrict__ Wh2h, const unsigned short* __restrict__ Wh2l,
    const float* __restrict__ bh2,
    float* __restrict__ out)
{
    __shared__ __attribute__((aligned(16))) unsigned short L[32768];
    unsigned short* Ah = L;
    unsigned short* Al = L + 8192;
    unsigned short* Bh = L + 16384;
    unsigned short* Bl = L + 24576;
    float* tf = reinterpret_cast<float*>(L + 16384);
    const int tid = threadIdx.x;
    const int lane = tid & 63, w = tid >> 6;
    const int lm = lane & 15, lq = lane >> 4;
    const int g0 = blockIdx.x * 32;

    {   // load hw tile [32x256] -> A hi/lo swizzled
        const float4* hp = reinterpret_cast<const float4*>(hw + (size_t)g0 * 256);
        #pragma unroll
        for (int i = 0; i < 4; i++) {
            int e = tid + 512 * i;
            int row = e >> 6, c0 = (e & 63) * 4;
            float4 u = hp[e];
            float vals[4] = {u.x, u.y, u.z, u.w};
            unsigned short vh[4], vl[4];
            #pragma unroll
            for (int j = 0; j < 4; j++) {
                vh[j] = f2bf(vals[j]);
                vl[j] = f2bf(vals[j] - bf2f(vh[j]));
            }
            int idx = swz(row, c0, 256);
            *reinterpret_cast<uint2*>(&Ah[idx]) = *reinterpret_cast<uint2*>(vh);
            *reinterpret_cast<uint2*>(&Al[idx]) = *reinterpret_cast<uint2*>(vl);
        }
    }
    __syncthreads();
    // P: pooled = hw @ G + d          (A -> B)
    tail_stage(Ah, Al, Gh, Gl, Gd, false, Bh, Bl, nullptr, w, lane, lm, lq);
    __syncthreads();
    // Q: ra = relu(pooled @ W_out + b_out)   (B -> A)
    tail_stage(Bh, Bl, Woh, Wol, b_out, true, Ah, Al, nullptr, w, lane, lm, lq);
    __syncthreads();
    // R: t = relu(ra @ Wh1 + bh1)     (A -> tf fp32 in B region)
    tail_stage(Ah, Al, Wh1h, Wh1l, bh1, true, nullptr, nullptr, tf, w, lane, lm, lq);
    __syncthreads();
    {   // LN per row (16 threads per row), write normalized bf16 hi/lo -> A
        const int row = tid >> 4, l16 = tid & 15;
        float s = 0.f;
        #pragma unroll
        for (int k = 0; k < 16; k++) s += tf[row * 256 + l16 + 16 * k];
        #pragma unroll
        for (int m = 1; m < 16; m <<= 1) s += __shfl_xor(s, m, 16);
        float mu = s * (1.f / 256.f);
        float v = 0.f;
        #pragma unroll
        for (int k = 0; k < 16; k++) {
            float d = tf[row * 256 + l16 + 16 * k] - mu;
            v += d * d;
        }
        #pragma unroll
        for (int m = 1; m < 16; m <<= 1) v += __shfl_xor(v, m, 16);
        float rs = rsqrtf(v * (1.f / 256.f) + 1e-5f);
        #pragma unroll
        for (int k = 0; k < 16; k++) {
            int col = l16 + 16 * k;
            float val = (tf[row * 256 + col] - mu) * rs * ln_g[col] + ln_b[col];
            unsigned short hi = f2bf(val);
            int idx = swz(row, col, 256);
            Ah[idx] = hi;
            Al[idx] = f2bf(val - bf2f(hi));
        }
    }
    __syncthreads();
    {   // S: out = t @ Wh2 + bh2   [32x256]@[256x1024]
        f32x4 acc[8][2];
        #pragma unroll
        for (int f = 0; f < 8; f++) {
            float bv = bh2[(8 * w + f) * 16 + lm];
            acc[f][0] = f32x4{bv, bv, bv, bv};
            acc[f][1] = acc[f][0];
        }
        #pragma unroll
        for (int ks = 0; ks < 8; ks++) {
            short8v ah0 = *reinterpret_cast<const short8v*>(&Ah[swz(lm, ks * 32 + lq * 8, 256)]);
            short8v al0 = *reinterpret_cast<const short8v*>(&Al[swz(lm, ks * 32 + lq * 8, 256)]);
            short8v ah1 = *reinterpret_cast<const short8v*>(&Ah[swz(16 + lm, ks * 32 + lq * 8, 256)]);
            short8v al1 = *reinterpret_cast<const short8v*>(&Al[swz(16 + lm, ks * 32 + lq * 8, 256)]);
            #pragma unroll
            for (int f = 0; f < 8; f++) {
                size_t bi = ((size_t)((8 * w + f) * 8 + ks) * 64 + lane) * 8;
                short8v bh = *reinterpret_cast<const short8v*>(Wh2h + bi);
                short8v bl = *reinterpret_cast<const short8v*>(Wh2l + bi);
                acc[f][0] = MFMA16(ah0, bh, acc[f][0]);
                acc[f][0] = MFMA16(al0, bh, acc[f][0]);
                acc[f][0] = MFMA16(ah0, bl, acc[f][0]);
                acc[f][1] = MFMA16(ah1, bh, acc[f][1]);
                acc[f][1] = MFMA16(al1, bh, acc[f][1]);
                acc[f][1] = MFMA16(ah1, bl, acc[f][1]);
            }
        }
        #pragma unroll
        for (int f = 0; f < 8; f++)
            #pragma unroll
            for (int m = 0; m < 2; m++)
                #pragma unroll
                for (int r = 0; r < 4; r++)
                    out[(size_t)(g0 + m * 16 + lq * 4 + r) * 1024 + (8 * w + f) * 16 + lm]
                        = acc[f][m][r];
    }
}

extern "C" void kernel_launch(void* const* d_in, const int* in_sizes, int n_in,
                              void* d_out, int out_size, void* d_ws, size_t ws_size,
                              hipStream_t stream) {
    const float* x       = (const float*)d_in[0];
    const int*   edge    = (const int*)d_in[1];
    const float* W_embed = (const float*)d_in[3];
    const float* b_embed = (const float*)d_in[4];
    const float* W1 = (const float*)d_in[5];
    const float* b1 = (const float*)d_in[6];
    const float* W2 = (const float*)d_in[7];
    const float* b2 = (const float*)d_in[8];
    const float* W3 = (const float*)d_in[9];
    const float* b3 = (const float*)d_in[10];
    const float* Wp = (const float*)d_in[11];
    const float* bp = (const float*)d_in[12];
    const float* q  = (const float*)d_in[13];
    const float* W_in  = (const float*)d_in[14];
    const float* b_in  = (const float*)d_in[15];
    const float* W_out = (const float*)d_in[16];
    const float* b_out = (const float*)d_in[17];
    const float* Wh1 = (const float*)d_in[18];
    const float* bh1 = (const float*)d_in[19];
    const float* ln_g = (const float*)d_in[20];
    const float* ln_b = (const float*)d_in[21];
    const float* Wh2 = (const float*)d_in[22];
    const float* bh2 = (const float*)d_in[23];
    float* out = (float*)d_out;

    char* ws = (char*)d_ws;
    int*   cnt  = (int*)(ws + 0);
    float* h    = (float*)(ws + 393216);
    float* hw   = (float*)(ws + 25559040);
    float* prec = (float*)(ws + 27656192);
    unsigned short* W1h = (unsigned short*)(ws + 27657232);
    unsigned short* W1l = (unsigned short*)(ws + 27853840);
    unsigned short* W2h = (unsigned short*)(ws + 28050448);
    unsigned short* W2l = (unsigned short*)(ws + 29623312);
    unsigned short* W3h = (unsigned short*)(ws + 31196176);
    unsigned short* W3l = (unsigned short*)(ws + 31589392);
    unsigned short* Weh = (unsigned short*)(ws + 31982608);
    unsigned short* Wel = (unsigned short*)(ws + 31998992);
    float* Gm  = (float*)(ws + 32015376);                    // 256*256*4 = 262144
    float* Gd  = (float*)(ws + 32277520);                    // 256*4 -> pad 1024
    unsigned short* Gfh  = (unsigned short*)(ws + 32278544); // 131072
    unsigned short* Gfl  = (unsigned short*)(ws + 32409616);
    unsigned short* Wofh = (unsigned short*)(ws + 32540688);
    unsigned short* Wofl = (unsigned short*)(ws + 32671760);
    unsigned short* Wh1fh= (unsigned short*)(ws + 32802832);
    unsigned short* Wh1fl= (unsigned short*)(ws + 32933904);
    unsigned short* Wh2fh= (unsigned short*)(ws + 33064976); // 524288
    unsigned short* Wh2fl= (unsigned short*)(ws + 33589264); // end 34113552

    zero_cnt_kernel<<<N_NODES / 256, 256, 0, stream>>>(cnt);
    hist_kernel<<<N_EDGES / 256, 256, 0, stream>>>(edge, cnt);

    prep_frag_kernel<<<1 * (64 / 16) * (128 / 32), 64, 0, stream>>>(W_embed, Weh, Wel, 128, 64);
    prep_frag_kernel<<<6 * (256 / 16) * (64 / 32), 64, 0, stream>>>(W1, W1h, W1l, 64, 256);
    prep_frag_kernel<<<6 * (512 / 16) * (256 / 32), 64, 0, stream>>>(W2, W2h, W2l, 256, 512);
    prep_frag_kernel<<<6 * (64 / 16) * (512 / 32), 64, 0, stream>>>(W3, W3h, W3l, 512, 64);

    gbuild_kernel<<<256, 256, 0, stream>>>(Wp, bp, W_in, b_in, Gm, Gd);
    prep_frag_kernel<<<(256 / 16) * (256 / 32), 64, 0, stream>>>(Gm, Gfh, Gfl, 256, 256);
    prep_frag_kernel<<<(256 / 16) * (256 / 32), 64, 0, stream>>>(W_out, Wofh, Wofl, 256, 256);
    prep_frag_kernel<<<(256 / 16) * (256 / 32), 64, 0, stream>>>(Wh1, Wh1fh, Wh1fl, 256, 256);
    prep_frag_kernel<<<(1024 / 16) * (256 / 32), 64, 0, stream>>>(Wh2, Wh2fh, Wh2fl, 256, 1024);

    embed_mfma_kernel<<<N_NODES / 32, 256, 0, stream>>>(x, Weh, Wel, b_embed, h);
    for (int l = 0; l < N_LAYERS_; l++) {
        layer_mfma_kernel<<<N_NODES / 32, 512, 0, stream>>>(
            h, cnt,
            W1h + (size_t)l * EMB * HID,     W1l + (size_t)l * EMB * HID,     b1 + (size_t)l * HID,
            W2h + (size_t)l * HID * 2 * HID, W2l + (size_t)l * HID * 2 * HID, b2 + (size_t)l * 2 * HID,
            W3h + (size_t)l * 2 * HID * EMB, W3l + (size_t)l * 2 * HID * EMB, b3 + (size_t)l * EMB);
    }
    prec_kernel<<<1, 256, 0, stream>>>(q, W_in, b_in, Wp, bp, prec);
    attnpool_kernel<<<N_GRAPHS, 64, 0, stream>>>(h, prec, hw);
    tail_mfma_kernel<<<N_GRAPHS / 32, 512, 0, stream>>>(
        hw, Gfh, Gfl, Gd, Wofh, Wofl, b_out, Wh1fh, Wh1fl, bh1,
        ln_g, ln_b, Wh2fh, Wh2fl, bh2, out);
}

// Round 6
// 877.492 us; speedup vs baseline: 12.2480x; 1.0054x over previous
//
#include <hip/hip_runtime.h>
#include <hip/hip_bf16.h>

#define N_NODES 98304
#define N_GRAPHS 2048
#define N_EDGES 393216
#define EMB 64
#define HID 256
#define N_LAYERS_ 6

typedef __attribute__((ext_vector_type(8))) short short8v;
typedef __attribute__((ext_vector_type(4))) float f32x4;
#define MFMA16(a, b, c) __builtin_amdgcn_mfma_f32_16x16x32_bf16(a, b, c, 0, 0, 0)

__device__ __forceinline__ unsigned short f2bf(float x) {
    unsigned int u = __float_as_uint(x);
    u = (u + 0x7fffu + ((u >> 16) & 1u)) >> 16;
    return (unsigned short)u;
}
__device__ __forceinline__ float bf2f(unsigned short h) {
    return __uint_as_float(((unsigned int)h) << 16);
}
// pack 2 floats -> 2 bf16 (RNE): low16 = a, high16 = b
__device__ __forceinline__ unsigned int cvtpk(float a, float b) {
    unsigned int r;
    asm("v_cvt_pk_bf16_f32 %0, %1, %2" : "=v"(r) : "v"(a), "v"(b));
    return r;
}
// swizzled index in ushort units: XOR bits 3..5 (16B-slot id) with row&7
__device__ __forceinline__ int swz(int row, int col, int rowc) {
    return (row * rowc + col) ^ ((row & 7) << 3);
}

// ---------------- histogram of edge rows ----------------
__global__ __launch_bounds__(256) void zero_cnt_kernel(int* __restrict__ cnt) {
    int i = blockIdx.x * 256 + threadIdx.x;
    if (i < N_NODES) cnt[i] = 0;
}
__global__ __launch_bounds__(256) void hist_kernel(const int* __restrict__ row,
                                                   int* __restrict__ cnt) {
    int i = blockIdx.x * 256 + threadIdx.x;
    if (i < N_EDGES) atomicAdd(&cnt[row[i]], 1);
}

// ---------------- weight prep: fp32 [L][K][N] -> hi/lo bf16 MFMA B-frags ----
__global__ __launch_bounds__(64) void prep_frag_kernel(
    const float* __restrict__ W, unsigned short* __restrict__ oh,
    unsigned short* __restrict__ ol, int K, int N)
{
    const int NF = N >> 4, KS = K >> 5;
    const int fpl = NF * KS;
    const int layer = blockIdx.x / fpl;
    const int fid = blockIdx.x % fpl;
    const int nf = fid / KS, ks = fid % KS;
    const int lane = threadIdx.x;
    const float* Wl = W + (size_t)layer * K * N;
    const int n = nf * 16 + (lane & 15);
    const int kb = ks * 32 + (lane >> 4) * 8;
    short8v vh, vl;
    #pragma unroll
    for (int j = 0; j < 8; j++) {
        float wv = Wl[(size_t)(kb + j) * N + n];
        unsigned short hi = f2bf(wv);
        vh[j] = (short)hi;
        vl[j] = (short)f2bf(wv - bf2f(hi));
    }
    size_t o = (size_t)layer * K * N + ((size_t)(nf * KS + ks) * 64 + lane) * 8;
    *reinterpret_cast<short8v*>(oh + o) = vh;
    *reinterpret_cast<short8v*>(ol + o) = vl;
}

// ---------------- G = per-head (Wp @ Wv) fold + d vector --------------------
__global__ __launch_bounds__(256) void gbuild_kernel(
    const float* __restrict__ Wp, const float* __restrict__ bp,
    const float* __restrict__ W_in, const float* __restrict__ b_in,
    float* __restrict__ Gm, float* __restrict__ Gd)
{
    const int idx = blockIdx.x * 256 + threadIdx.x;
    const int q = idx >> 8, p = idx & 255;
    float s = 0.f;
    if ((q >> 6) == (p >> 6)) {
        const float* wr = Wp + (q & 63) * 256;
        for (int j = 0; j < 256; j++) s += wr[j] * W_in[j * 768 + 512 + p];
    }
    Gm[q * 256 + p] = s;
    if (blockIdx.x == 0) {
        const int pp = threadIdx.x;
        float dsum = b_in[512 + pp];
        for (int j = 0; j < 256; j++) dsum += bp[j] * W_in[j * 768 + 512 + pp];
        Gd[pp] = dsum;
    }
}

// ---------------- embed via split MFMA: h = x @ W_embed + b -----------------
__global__ __launch_bounds__(256) void embed_mfma_kernel(
    const float* __restrict__ x,
    const unsigned short* __restrict__ Weh, const unsigned short* __restrict__ Wel,
    const float* __restrict__ b, float* __restrict__ h)
{
    __shared__ __attribute__((aligned(16))) unsigned short xh[32 * 128];
    __shared__ __attribute__((aligned(16))) unsigned short xl[32 * 128];
    const int tid = threadIdx.x;
    const int lane = tid & 63, w = tid >> 6;
    const int lm = lane & 15, lq = lane >> 4;
    const int base = blockIdx.x * 32;
    {
        int row = tid >> 3, c0 = (tid & 7) * 16;
        const float4* p = reinterpret_cast<const float4*>(x + (size_t)(base + row) * 128 + c0);
        #pragma unroll
        for (int g = 0; g < 4; g++) {
            float4 u = p[g];
            unsigned int p01 = cvtpk(u.x, u.y);
            unsigned int p23 = cvtpk(u.z, u.w);
            float h0 = __uint_as_float(p01 << 16), h1 = __uint_as_float(p01 & 0xffff0000u);
            float h2 = __uint_as_float(p23 << 16), h3 = __uint_as_float(p23 & 0xffff0000u);
            unsigned int q01 = cvtpk(u.x - h0, u.y - h1);
            unsigned int q23 = cvtpk(u.z - h2, u.w - h3);
            int idx = swz(row, c0 + g * 4, 128);
            *reinterpret_cast<uint2*>(&xh[idx]) = make_uint2(p01, p23);
            *reinterpret_cast<uint2*>(&xl[idx]) = make_uint2(q01, q23);
        }
    }
    __syncthreads();
    f32x4 acc0, acc1;
    {
        float bv = b[w * 16 + lm];
        acc0 = f32x4{bv, bv, bv, bv};
        acc1 = acc0;
    }
    #pragma unroll
    for (int ks = 0; ks < 4; ks++) {
        short8v a0h = *reinterpret_cast<const short8v*>(&xh[swz(lm, ks * 32 + lq * 8, 128)]);
        short8v a0l = *reinterpret_cast<const short8v*>(&xl[swz(lm, ks * 32 + lq * 8, 128)]);
        short8v a1h = *reinterpret_cast<const short8v*>(&xh[swz(16 + lm, ks * 32 + lq * 8, 128)]);
        short8v a1l = *reinterpret_cast<const short8v*>(&xl[swz(16 + lm, ks * 32 + lq * 8, 128)]);
        size_t bi = ((size_t)(w * 4 + ks) * 64 + lane) * 8;
        short8v bh = *reinterpret_cast<const short8v*>(Weh + bi);
        short8v bl = *reinterpret_cast<const short8v*>(Wel + bi);
        acc0 = MFMA16(a0h, bh, acc0); acc0 = MFMA16(a0l, bh, acc0); acc0 = MFMA16(a0h, bl, acc0);
        acc1 = MFMA16(a1h, bh, acc1); acc1 = MFMA16(a1l, bh, acc1); acc1 = MFMA16(a1h, bl, acc1);
    }
    #pragma unroll
    for (int r = 0; r < 4; r++) {
        h[(size_t)(base + lq * 4 + r) * 64 + w * 16 + lm] = acc0[r];
        h[(size_t)(base + 16 + lq * 4 + r) * 64 + w * 16 + lm] = acc1[r];
    }
}

// ---- helper: split-convert 4 row-consecutive accs and store hi/lo to LDS ---
__device__ __forceinline__ void store_quad(
    unsigned short* __restrict__ oh, unsigned short* __restrict__ ol,
    float v0, float v1, float v2, float v3,
    int row0, int col, int rowc)
{
    unsigned int p01 = cvtpk(v0, v1);
    unsigned int p23 = cvtpk(v2, v3);
    float h0 = __uint_as_float(p01 << 16), h1 = __uint_as_float(p01 & 0xffff0000u);
    float h2 = __uint_as_float(p23 << 16), h3 = __uint_as_float(p23 & 0xffff0000u);
    unsigned int q01 = cvtpk(v0 - h0, v1 - h1);
    unsigned int q23 = cvtpk(v2 - h2, v3 - h3);
    oh[swz(row0 + 0, col, rowc)] = (unsigned short)p01;
    oh[swz(row0 + 1, col, rowc)] = (unsigned short)(p01 >> 16);
    oh[swz(row0 + 2, col, rowc)] = (unsigned short)p23;
    oh[swz(row0 + 3, col, rowc)] = (unsigned short)(p23 >> 16);
    ol[swz(row0 + 0, col, rowc)] = (unsigned short)q01;
    ol[swz(row0 + 1, col, rowc)] = (unsigned short)(q01 >> 16);
    ol[swz(row0 + 2, col, rowc)] = (unsigned short)q23;
    ol[swz(row0 + 3, col, rowc)] = (unsigned short)(q23 >> 16);
}

// ---------------- fused MLP layer, split-bf16 MFMA, v3 ----------------------
// 32 nodes/block, 8 waves, LDS 48KB -> 3 blocks/CU (6 waves/SIMD).
// m2 chunked to [32x128] x 4; m2-hi LDS unions with hs (dead after stage A).
__global__ __launch_bounds__(512, 6) void layer_mfma_kernel(
    float* __restrict__ h, const int* __restrict__ cnt,
    const unsigned short* __restrict__ W1h, const unsigned short* __restrict__ W1l,
    const float* __restrict__ b1,
    const unsigned short* __restrict__ W2h, const unsigned short* __restrict__ W2l,
    const float* __restrict__ b2,
    const unsigned short* __restrict__ W3h, const unsigned short* __restrict__ W3l,
    const float* __restrict__ b3)
{
    __shared__ __attribute__((aligned(16))) unsigned short R0[4096];    // hs -> m2h chunk
    __shared__ __attribute__((aligned(16))) unsigned short m1h_[8192];  // 16KB
    __shared__ __attribute__((aligned(16))) unsigned short m1l_[8192];  // 16KB
    __shared__ __attribute__((aligned(16))) unsigned short m2l_[4096];  // 8KB
    unsigned short* hsh = R0;            // 32x64
    unsigned short* hsl = R0 + 2048;
    unsigned short* m2h_ = R0;           // 32x128 (after stage A)
    const int tid = threadIdx.x;
    const int lane = tid & 63, w = tid >> 6;
    const int lm = lane & 15, lq = lane >> 4;
    const int base = blockIdx.x * 32;

    {   // stage 0: h tile (fp32 32x64) -> hi/lo bf16 planes, uint2 stores
        int row = tid >> 4, c0 = (tid & 15) * 4;
        const float4 u = *reinterpret_cast<const float4*>(h + (size_t)(base + row) * 64 + c0);
        unsigned int p01 = cvtpk(u.x, u.y);
        unsigned int p23 = cvtpk(u.z, u.w);
        float h0 = __uint_as_float(p01 << 16), h1 = __uint_as_float(p01 & 0xffff0000u);
        float h2 = __uint_as_float(p23 << 16), h3 = __uint_as_float(p23 & 0xffff0000u);
        unsigned int q01 = cvtpk(u.x - h0, u.y - h1);
        unsigned int q23 = cvtpk(u.z - h2, u.w - h3);
        int idx = swz(row, c0, 64);
        *reinterpret_cast<uint2*>(&hsh[idx]) = make_uint2(p01, p23);
        *reinterpret_cast<uint2*>(&hsl[idx]) = make_uint2(q01, q23);
    }
    __syncthreads();

    // ---- stage A: m1 = relu(hs @ W1 + b1)  [32x256]; wave w -> frags {2w,2w+1}
    {
        f32x4 acc[2][2];   // [f][m]
        #pragma unroll
        for (int f = 0; f < 2; f++) {
            float bv = b1[(2 * w + f) * 16 + lm];
            acc[f][0] = f32x4{bv, bv, bv, bv};
            acc[f][1] = acc[f][0];
        }
        #pragma unroll
        for (int ks = 0; ks < 2; ks++) {
            short8v ah0 = *reinterpret_cast<const short8v*>(&hsh[swz(lm, ks * 32 + lq * 8, 64)]);
            short8v al0 = *reinterpret_cast<const short8v*>(&hsl[swz(lm, ks * 32 + lq * 8, 64)]);
            short8v ah1 = *reinterpret_cast<const short8v*>(&hsh[swz(16 + lm, ks * 32 + lq * 8, 64)]);
            short8v al1 = *reinterpret_cast<const short8v*>(&hsl[swz(16 + lm, ks * 32 + lq * 8, 64)]);
            #pragma unroll
            for (int f = 0; f < 2; f++) {
                size_t bi = ((size_t)((2 * w + f) * 2 + ks) * 64 + lane) * 8;
                short8v bh = *reinterpret_cast<const short8v*>(W1h + bi);
                short8v bl = *reinterpret_cast<const short8v*>(W1l + bi);
                acc[f][0] = MFMA16(ah0, bh, acc[f][0]);
                acc[f][0] = MFMA16(al0, bh, acc[f][0]);
                acc[f][0] = MFMA16(ah0, bl, acc[f][0]);
                acc[f][1] = MFMA16(ah1, bh, acc[f][1]);
                acc[f][1] = MFMA16(al1, bh, acc[f][1]);
                acc[f][1] = MFMA16(ah1, bl, acc[f][1]);
            }
        }
        #pragma unroll
        for (int f = 0; f < 2; f++)
            #pragma unroll
            for (int m = 0; m < 2; m++)
                store_quad(m1h_, m1l_,
                           fmaxf(acc[f][m][0], 0.f), fmaxf(acc[f][m][1], 0.f),
                           fmaxf(acc[f][m][2], 0.f), fmaxf(acc[f][m][3], 0.f),
                           m * 16 + lq * 4, (2 * w + f) * 16 + lm, 256);
    }
    __syncthreads();

    // persistent stage-C accumulators: wave -> nfc = w&3 (cols), kq = w>>2 (k-half)
    const int nfc = w & 3, kq = w >> 2;
    f32x4 dacc[2];
    if (kq == 0) {
        float bv = b3[nfc * 16 + lm];
        dacc[0] = f32x4{bv, bv, bv, bv};
    } else {
        dacc[0] = f32x4{0.f, 0.f, 0.f, 0.f};
    }
    dacc[1] = dacc[0];

    #pragma unroll
    for (int c = 0; c < 4; ++c) {
        // ---- stage B: m2c = relu(m1 @ W2[:, c*128:+128] + b2); wave -> frag w
        {
            const int nfg = c * 8 + w;
            f32x4 acc[2];
            {
                float bv = b2[nfg * 16 + lm];
                acc[0] = f32x4{bv, bv, bv, bv};
                acc[1] = acc[0];
            }
            #pragma unroll
            for (int ks = 0; ks < 8; ks++) {
                short8v ah0 = *reinterpret_cast<const short8v*>(&m1h_[swz(lm, ks * 32 + lq * 8, 256)]);
                short8v al0 = *reinterpret_cast<const short8v*>(&m1l_[swz(lm, ks * 32 + lq * 8, 256)]);
                short8v ah1 = *reinterpret_cast<const short8v*>(&m1h_[swz(16 + lm, ks * 32 + lq * 8, 256)]);
                short8v al1 = *reinterpret_cast<const short8v*>(&m1l_[swz(16 + lm, ks * 32 + lq * 8, 256)]);
                size_t bi = ((size_t)(nfg * 8 + ks) * 64 + lane) * 8;
                short8v bh = *reinterpret_cast<const short8v*>(W2h + bi);
                short8v bl = *reinterpret_cast<const short8v*>(W2l + bi);
                acc[0] = MFMA16(ah0, bh, acc[0]);
                acc[0] = MFMA16(al0, bh, acc[0]);
                acc[0] = MFMA16(ah0, bl, acc[0]);
                acc[1] = MFMA16(ah1, bh, acc[1]);
                acc[1] = MFMA16(al1, bh, acc[1]);
                acc[1] = MFMA16(ah1, bl, acc[1]);
            }
            #pragma unroll
            for (int m = 0; m < 2; m++)
                store_quad(m2h_, m2l_,
                           fmaxf(acc[m][0], 0.f), fmaxf(acc[m][1], 0.f),
                           fmaxf(acc[m][2], 0.f), fmaxf(acc[m][3], 0.f),
                           m * 16 + lq * 4, w * 16 + lm, 128);
        }
        __syncthreads();
        // ---- stage C partial: dacc += m2c[:, kq-half] @ W3[c*128 + ...] ----
        {
            #pragma unroll
            for (int kl = 0; kl < 2; kl++) {
                int ksl = kq * 2 + kl;
                short8v ah0 = *reinterpret_cast<const short8v*>(&m2h_[swz(lm, ksl * 32 + lq * 8, 128)]);
                short8v al0 = *reinterpret_cast<const short8v*>(&m2l_[swz(lm, ksl * 32 + lq * 8, 128)]);
                short8v ah1 = *reinterpret_cast<const short8v*>(&m2h_[swz(16 + lm, ksl * 32 + lq * 8, 128)]);
                short8v al1 = *reinterpret_cast<const short8v*>(&m2l_[swz(16 + lm, ksl * 32 + lq * 8, 128)]);
                int ksg = c * 4 + ksl;
                size_t bi = ((size_t)(nfc * 16 + ksg) * 64 + lane) * 8;
                short8v bh = *reinterpret_cast<const short8v*>(W3h + bi);
                short8v bl = *reinterpret_cast<const short8v*>(W3l + bi);
                dacc[0] = MFMA16(ah0, bh, dacc[0]);
                dacc[0] = MFMA16(al0, bh, dacc[0]);
                dacc[0] = MFMA16(ah0, bl, dacc[0]);
                dacc[1] = MFMA16(ah1, bh, dacc[1]);
                dacc[1] = MFMA16(al1, bh, dacc[1]);
                dacc[1] = MFMA16(ah1, bl, dacc[1]);
            }
        }
        __syncthreads();   // all C reads done before next chunk's B writes
    }

    // ---- combine kq halves via fp32 scratch (reuse m1 LDS), epilogue -------
    float* scr = reinterpret_cast<float*>(m1h_);   // 32*64 f32 = 8KB <= 16KB
    if (kq == 1) {
        #pragma unroll
        for (int m = 0; m < 2; m++)
            #pragma unroll
            for (int r = 0; r < 4; r++)
                scr[(m * 16 + lq * 4 + r) * 64 + nfc * 16 + lm] = dacc[m][r];
    }
    __syncthreads();
    if (kq == 0) {
        #pragma unroll
        for (int m = 0; m < 2; m++)
            #pragma unroll
            for (int r = 0; r < 4; r++) {
                int rr = base + m * 16 + lq * 4 + r;
                float dv = dacc[m][r] + scr[(m * 16 + lq * 4 + r) * 64 + nfc * 16 + lm];
                size_t gi = (size_t)rr * 64 + nfc * 16 + lm;
                h[gi] = h[gi] + (float)cnt[rr] * dv;
            }
    }
}

// ---------------- precompute score vectors (fp32) ---------------------------
__global__ __launch_bounds__(256) void prec_kernel(
    const float* __restrict__ q, const float* __restrict__ W_in,
    const float* __restrict__ b_in, const float* __restrict__ Wp,
    const float* __restrict__ bp, float* __restrict__ prec)
{
    __shared__ float qh_s[256];
    __shared__ float u_s[4 * 256];
    const int tid = threadIdx.x;
    {
        float acc = b_in[tid];
        for (int j = 0; j < 256; j++) acc += q[j] * W_in[j * 768 + tid];
        qh_s[tid] = acc * 0.125f;
    }
    __syncthreads();
    {
        #pragma unroll
        for (int hd = 0; hd < 4; hd++) {
            float a = 0.f;
            for (int d = 0; d < 64; d++)
                a += W_in[tid * 768 + 256 + hd * 64 + d] * qh_s[hd * 64 + d];
            u_s[hd * 256 + tid] = a;
        }
    }
    __syncthreads();
    {
        int hd = tid >> 6, i = tid & 63;
        float a = 0.f;
        for (int j = 0; j < 256; j++) a += Wp[i * 256 + j] * u_s[hd * 256 + j];
        prec[hd * 64 + i] = a;
    }
    if (tid < 4) {
        float a = 0.f;
        for (int j = 0; j < 256; j++) a += bp[j] * u_s[tid * 256 + j];
        for (int d = 0; d < 64; d++) a += b_in[256 + tid * 64 + d] * qh_s[tid * 64 + d];
        prec[256 + tid] = a;
    }
}

// ---------------- attention pooling (fp32) ----------------------------------
__global__ __launch_bounds__(64) void attnpool_kernel(
    const float* __restrict__ h, const float* __restrict__ prec,
    float* __restrict__ hw)
{
    __shared__ float hs[48 * 65];
    __shared__ float ss[4 * 64];
    __shared__ float ds_[4];
    __shared__ float wl[48 * 4];
    const int lane = threadIdx.x;
    const int g = blockIdx.x;
    #pragma unroll
    for (int hd = 0; hd < 4; hd++) ss[hd * 64 + lane] = prec[hd * 64 + lane];
    if (lane < 4) ds_[lane] = prec[256 + lane];
    for (int r = 0; r < 48; r++)
        hs[r * 65 + lane] = h[((size_t)g * 48 + r) * 64 + lane];
    __syncthreads();
    float sc[4] = {0.f, 0.f, 0.f, 0.f};
    if (lane < 48) {
        #pragma unroll
        for (int hd = 0; hd < 4; hd++) sc[hd] = ds_[hd];
        for (int c = 0; c < 64; c++) {
            float a = hs[lane * 65 + c];
            #pragma unroll
            for (int hd = 0; hd < 4; hd++) sc[hd] += a * ss[hd * 64 + c];
        }
    }
    #pragma unroll
    for (int hd = 0; hd < 4; hd++) {
        float v = (lane < 48) ? sc[hd] : -3.0e38f;
        #pragma unroll
        for (int m = 32; m >= 1; m >>= 1) v = fmaxf(v, __shfl_xor(v, m, 64));
        float e = (lane < 48) ? __expf(sc[hd] - v) : 0.f;
        float s = e;
        #pragma unroll
        for (int m = 32; m >= 1; m >>= 1) s += __shfl_xor(s, m, 64);
        if (lane < 48) wl[lane * 4 + hd] = e / s;
    }
    __syncthreads();
    float acc[4] = {0.f, 0.f, 0.f, 0.f};
    for (int n = 0; n < 48; n++) {
        float hv = hs[n * 65 + lane];
        #pragma unroll
        for (int hd = 0; hd < 4; hd++) acc[hd] += wl[n * 4 + hd] * hv;
    }
    #pragma unroll
    for (int hd = 0; hd < 4; hd++) hw[(size_t)g * 256 + hd * 64 + lane] = acc[hd];
}

// ---------------- tail stage helper: [32x256] @ [256x256] split-bf16 --------
__device__ __forceinline__ void tail_stage(
    const unsigned short* __restrict__ inh, const unsigned short* __restrict__ inl,
    const unsigned short* __restrict__ wh, const unsigned short* __restrict__ wl,
    const float* __restrict__ bias, const bool do_relu,
    unsigned short* __restrict__ oth, unsigned short* __restrict__ otl,
    float* __restrict__ tf32,
    const int w, const int lane, const int lm, const int lq)
{
    f32x4 acc[2][2];
    #pragma unroll
    for (int f = 0; f < 2; f++) {
        float bv = bias[(2 * w + f) * 16 + lm];
        acc[f][0] = f32x4{bv, bv, bv, bv};
        acc[f][1] = acc[f][0];
    }
    #pragma unroll
    for (int ks = 0; ks < 8; ks++) {
        short8v ah0 = *reinterpret_cast<const short8v*>(&inh[swz(lm, ks * 32 + lq * 8, 256)]);
        short8v al0 = *reinterpret_cast<const short8v*>(&inl[swz(lm, ks * 32 + lq * 8, 256)]);
        short8v ah1 = *reinterpret_cast<const short8v*>(&inh[swz(16 + lm, ks * 32 + lq * 8, 256)]);
        short8v al1 = *reinterpret_cast<const short8v*>(&inl[swz(16 + lm, ks * 32 + lq * 8, 256)]);
        #pragma unroll
        for (int f = 0; f < 2; f++) {
            size_t bi = ((size_t)((2 * w + f) * 8 + ks) * 64 + lane) * 8;
            short8v bh = *reinterpret_cast<const short8v*>(wh + bi);
            short8v bl = *reinterpret_cast<const short8v*>(wl + bi);
            acc[f][0] = MFMA16(ah0, bh, acc[f][0]);
            acc[f][0] = MFMA16(al0, bh, acc[f][0]);
            acc[f][0] = MFMA16(ah0, bl, acc[f][0]);
            acc[f][1] = MFMA16(ah1, bh, acc[f][1]);
            acc[f][1] = MFMA16(al1, bh, acc[f][1]);
            acc[f][1] = MFMA16(ah1, bl, acc[f][1]);
        }
    }
    #pragma unroll
    for (int f = 0; f < 2; f++)
        #pragma unroll
        for (int m = 0; m < 2; m++) {
            if (tf32) {
                #pragma unroll
                for (int r = 0; r < 4; r++) {
                    float v = acc[f][m][r];
                    if (do_relu) v = fmaxf(v, 0.f);
                    tf32[(m * 16 + lq * 4 + r) * 256 + (2 * w + f) * 16 + lm] = v;
                }
            } else {
                float v0 = acc[f][m][0], v1 = acc[f][m][1], v2 = acc[f][m][2], v3 = acc[f][m][3];
                if (do_relu) {
                    v0 = fmaxf(v0, 0.f); v1 = fmaxf(v1, 0.f);
                    v2 = fmaxf(v2, 0.f); v3 = fmaxf(v3, 0.f);
                }
                store_quad(oth, otl, v0, v1, v2, v3,
                           m * 16 + lq * 4, (2 * w + f) * 16 + lm, 256);
            }
        }
}

// ---------------- fused MFMA tail: pooled->attn->t->LN->out -----------------
__global__ __launch_bounds__(512, 4) void tail_mfma_kernel(
    const float* __restrict__ hw,
    const unsigned short* __restrict__ Gh, const unsigned short* __restrict__ Gl,
    const float* __restrict__ Gd,
    const unsigned short* __restrict__ Woh, const unsigned short* __restrict__ Wol,
    const float* __restrict__ b_out,
    const unsigned short* __restrict__ Wh1h, const unsigned short* __restrict__ Wh1l,
    const float* __restrict__ bh1,
    const float* __restrict__ ln_g, const float* __restrict__ ln_b,
    const unsigned short* __restrict__ Wh2h, const unsigned short* __restrict__ Wh2l,
    const float* __restrict__ bh2,
    float* __restrict__ out)
{
    __shared__ __attribute__((aligned(16))) unsigned short L[32768];
    unsigned short* Ah = L;
    unsigned short* Al = L + 8192;
    unsigned short* Bh = L + 16384;
    unsigned short* Bl = L + 24576;
    float* tf = reinterpret_cast<float*>(L + 16384);
    const int tid = threadIdx.x;
    const int lane = tid & 63, w = tid >> 6;
    const int lm = lane & 15, lq = lane >> 4;
    const int g0 = blockIdx.x * 32;

    {   // load hw tile [32x256] -> A hi/lo swizzled
        const float4* hp = reinterpret_cast<const float4*>(hw + (size_t)g0 * 256);
        #pragma unroll
        for (int i = 0; i < 4; i++) {
            int e = tid + 512 * i;
            int row = e >> 6, c0 = (e & 63) * 4;
            float4 u = hp[e];
            unsigned int p01 = cvtpk(u.x, u.y);
            unsigned int p23 = cvtpk(u.z, u.w);
            float h0 = __uint_as_float(p01 << 16), h1 = __uint_as_float(p01 & 0xffff0000u);
            float h2 = __uint_as_float(p23 << 16), h3 = __uint_as_float(p23 & 0xffff0000u);
            unsigned int q01 = cvtpk(u.x - h0, u.y - h1);
            unsigned int q23 = cvtpk(u.z - h2, u.w - h3);
            int idx = swz(row, c0, 256);
            *reinterpret_cast<uint2*>(&Ah[idx]) = make_uint2(p01, p23);
            *reinterpret_cast<uint2*>(&Al[idx]) = make_uint2(q01, q23);
        }
    }
    __syncthreads();
    tail_stage(Ah, Al, Gh, Gl, Gd, false, Bh, Bl, nullptr, w, lane, lm, lq);
    __syncthreads();
    tail_stage(Bh, Bl, Woh, Wol, b_out, true, Ah, Al, nullptr, w, lane, lm, lq);
    __syncthreads();
    tail_stage(Ah, Al, Wh1h, Wh1l, bh1, true, nullptr, nullptr, tf, w, lane, lm, lq);
    __syncthreads();
    {   // LN per row (16 threads per row), write normalized bf16 hi/lo -> A
        const int row = tid >> 4, l16 = tid & 15;
        float s = 0.f;
        #pragma unroll
        for (int k = 0; k < 16; k++) s += tf[row * 256 + l16 + 16 * k];
        #pragma unroll
        for (int m = 1; m < 16; m <<= 1) s += __shfl_xor(s, m, 16);
        float mu = s * (1.f / 256.f);
        float v = 0.f;
        #pragma unroll
        for (int k = 0; k < 16; k++) {
            float d = tf[row * 256 + l16 + 16 * k] - mu;
            v += d * d;
        }
        #pragma unroll
        for (int m = 1; m < 16; m <<= 1) v += __shfl_xor(v, m, 16);
        float rs = rsqrtf(v * (1.f / 256.f) + 1e-5f);
        #pragma unroll
        for (int k = 0; k < 16; k++) {
            int col = l16 + 16 * k;
            float val = (tf[row * 256 + col] - mu) * rs * ln_g[col] + ln_b[col];
            unsigned short hi = f2bf(val);
            int idx = swz(row, col, 256);
            Ah[idx] = hi;
            Al[idx] = f2bf(val - bf2f(hi));
        }
    }
    __syncthreads();
    {   // S: out = t @ Wh2 + bh2   [32x256]@[256x1024]
        f32x4 acc[8][2];
        #pragma unroll
        for (int f = 0; f < 8; f++) {
            float bv = bh2[(8 * w + f) * 16 + lm];
            acc[f][0] = f32x4{bv, bv, bv, bv};
            acc[f][1] = acc[f][0];
        }
        #pragma unroll
        for (int ks = 0; ks < 8; ks++) {
            short8v ah0 = *reinterpret_cast<const short8v*>(&Ah[swz(lm, ks * 32 + lq * 8, 256)]);
            short8v al0 = *reinterpret_cast<const short8v*>(&Al[swz(lm, ks * 32 + lq * 8, 256)]);
            short8v ah1 = *reinterpret_cast<const short8v*>(&Ah[swz(16 + lm, ks * 32 + lq * 8, 256)]);
            short8v al1 = *reinterpret_cast<const short8v*>(&Al[swz(16 + lm, ks * 32 + lq * 8, 256)]);
            #pragma unroll
            for (int f = 0; f < 8; f++) {
                size_t bi = ((size_t)((8 * w + f) * 8 + ks) * 64 + lane) * 8;
                short8v bh = *reinterpret_cast<const short8v*>(Wh2h + bi);
                short8v bl = *reinterpret_cast<const short8v*>(Wh2l + bi);
                acc[f][0] = MFMA16(ah0, bh, acc[f][0]);
                acc[f][0] = MFMA16(al0, bh, acc[f][0]);
                acc[f][0] = MFMA16(ah0, bl, acc[f][0]);
                acc[f][1] = MFMA16(ah1, bh, acc[f][1]);
                acc[f][1] = MFMA16(al1, bh, acc[f][1]);
                acc[f][1] = MFMA16(ah1, bl, acc[f][1]);
            }
        }
        #pragma unroll
        for (int f = 0; f < 8; f++)
            #pragma unroll
            for (int m = 0; m < 2; m++)
                #pragma unroll
                for (int r = 0; r < 4; r++)
                    out[(size_t)(g0 + m * 16 + lq * 4 + r) * 1024 + (8 * w + f) * 16 + lm]
                        = acc[f][m][r];
    }
}

extern "C" void kernel_launch(void* const* d_in, const int* in_sizes, int n_in,
                              void* d_out, int out_size, void* d_ws, size_t ws_size,
                              hipStream_t stream) {
    const float* x       = (const float*)d_in[0];
    const int*   edge    = (const int*)d_in[1];
    const float* W_embed = (const float*)d_in[3];
    const float* b_embed = (const float*)d_in[4];
    const float* W1 = (const float*)d_in[5];
    const float* b1 = (const float*)d_in[6];
    const float* W2 = (const float*)d_in[7];
    const float* b2 = (const float*)d_in[8];
    const float* W3 = (const float*)d_in[9];
    const float* b3 = (const float*)d_in[10];
    const float* Wp = (const float*)d_in[11];
    const float* bp = (const float*)d_in[12];
    const float* q  = (const float*)d_in[13];
    const float* W_in  = (const float*)d_in[14];
    const float* b_in  = (const float*)d_in[15];
    const float* W_out = (const float*)d_in[16];
    const float* b_out = (const float*)d_in[17];
    const float* Wh1 = (const float*)d_in[18];
    const float* bh1 = (const float*)d_in[19];
    const float* ln_g = (const float*)d_in[20];
    const float* ln_b = (const float*)d_in[21];
    const float* Wh2 = (const float*)d_in[22];
    const float* bh2 = (const float*)d_in[23];
    float* out = (float*)d_out;

    char* ws = (char*)d_ws;
    int*   cnt  = (int*)(ws + 0);
    float* h    = (float*)(ws + 393216);
    float* hw   = (float*)(ws + 25559040);
    float* prec = (float*)(ws + 27656192);
    unsigned short* W1h = (unsigned short*)(ws + 27657232);
    unsigned short* W1l = (unsigned short*)(ws + 27853840);
    unsigned short* W2h = (unsigned short*)(ws + 28050448);
    unsigned short* W2l = (unsigned short*)(ws + 29623312);
    unsigned short* W3h = (unsigned short*)(ws + 31196176);
    unsigned short* W3l = (unsigned short*)(ws + 31589392);
    unsigned short* Weh = (unsigned short*)(ws + 31982608);
    unsigned short* Wel = (unsigned short*)(ws + 31998992);
    float* Gm  = (float*)(ws + 32015376);
    float* Gd  = (float*)(ws + 32277520);
    unsigned short* Gfh  = (unsigned short*)(ws + 32278544);
    unsigned short* Gfl  = (unsigned short*)(ws + 32409616);
    unsigned short* Wofh = (unsigned short*)(ws + 32540688);
    unsigned short* Wofl = (unsigned short*)(ws + 32671760);
    unsigned short* Wh1fh= (unsigned short*)(ws + 32802832);
    unsigned short* Wh1fl= (unsigned short*)(ws + 32933904);
    unsigned short* Wh2fh= (unsigned short*)(ws + 33064976);
    unsigned short* Wh2fl= (unsigned short*)(ws + 33589264);

    zero_cnt_kernel<<<N_NODES / 256, 256, 0, stream>>>(cnt);
    hist_kernel<<<N_EDGES / 256, 256, 0, stream>>>(edge, cnt);

    prep_frag_kernel<<<1 * (64 / 16) * (128 / 32), 64, 0, stream>>>(W_embed, Weh, Wel, 128, 64);
    prep_frag_kernel<<<6 * (256 / 16) * (64 / 32), 64, 0, stream>>>(W1, W1h, W1l, 64, 256);
    prep_frag_kernel<<<6 * (512 / 16) * (256 / 32), 64, 0, stream>>>(W2, W2h, W2l, 256, 512);
    prep_frag_kernel<<<6 * (64 / 16) * (512 / 32), 64, 0, stream>>>(W3, W3h, W3l, 512, 64);

    gbuild_kernel<<<256, 256, 0, stream>>>(Wp, bp, W_in, b_in, Gm, Gd);
    prep_frag_kernel<<<(256 / 16) * (256 / 32), 64, 0, stream>>>(Gm, Gfh, Gfl, 256, 256);
    prep_frag_kernel<<<(256 / 16) * (256 / 32), 64, 0, stream>>>(W_out, Wofh, Wofl, 256, 256);
    prep_frag_kernel<<<(256 / 16) * (256 / 32), 64, 0, stream>>>(Wh1, Wh1fh, Wh1fl, 256, 256);
    prep_frag_kernel<<<(1024 / 16) * (256 / 32), 64, 0, stream>>>(Wh2, Wh2fh, Wh2fl, 256, 1024);

    embed_mfma_kernel<<<N_NODES / 32, 256, 0, stream>>>(x, Weh, Wel, b_embed, h);
    for (int l = 0; l < N_LAYERS_; l++) {
        layer_mfma_kernel<<<N_NODES / 32, 512, 0, stream>>>(
            h, cnt,
            W1h + (size_t)l * EMB * HID,     W1l + (size_t)l * EMB * HID,     b1 + (size_t)l * HID,
            W2h + (size_t)l * HID * 2 * HID, W2l + (size_t)l * HID * 2 * HID, b2 + (size_t)l * 2 * HID,
            W3h + (size_t)l * 2 * HID * EMB, W3l + (size_t)l * 2 * HID * EMB, b3 + (size_t)l * EMB);
    }
    prec_kernel<<<1, 256, 0, stream>>>(q, W_in, b_in, Wp, bp, prec);
    attnpool_kernel<<<N_GRAPHS, 64, 0, stream>>>(h, prec, hw);
    tail_mfma_kernel<<<N_GRAPHS / 32, 512, 0, stream>>>(
        hw, Gfh, Gfl, Gd, Wofh, Wofl, b_out, Wh1fh, Wh1fl, bh1,
        ln_g, ln_b, Wh2fh, Wh2fl, bh2, out);
}